// Round 5
// baseline (373.688 us; speedup 1.0000x reference)
//
#include <hip/hip_runtime.h>
#include <math.h>

// Problem constants
#define N0 80000
#define N1 40000
#define N2 20000
#define E1C 500000
#define E2C 250000
#define NTYPE 23
#define NTS 1158

// derived grid constants
#define NB1 157
#define NB2 79
#define KV1B 1250
#define QR1B 625
#define CNTB 2930
#define KV2B 625
#define QR2B 313
#define FILLB 2930
#define TCB  1800          // TC-build blocks riding csr_scan
#define NTC  (NTYPE * NTS) // 26634 combined edge-type rows

// ---------------- Workspace layout (float offsets) ----------------
#define OFF_XB    0u
#define OFF_TC1   0u        // overlays XB (dead after mega_l1); bf16, 26634*128
#define OFF_TC2   1710000u  // ends 3,414,576 < 5,120,000
#define OFF_QR1   5120000u
#define OFF_KV1   15360000u
#define OFF_H     25600000u
#define OFF_QR2   28160000u
#define OFF_KV2   32000000u
#define OFF_WB1   37120000u
#define OFF_BP1   37160000u
#define OFF_WB2   37170000u
#define OFF_BP2   37200000u
#define OFF_TA1   37210000u
#define OFF_TB1   37213000u
#define OFF_TA2   37370000u
#define OFF_TB2   37373000u
#define OFF_RP1   37530000u
#define OFF_CUR1  37580000u
#define OFF_ED1   37630000u
#define OFF_BS1   38640000u
#define OFF_RP2   38650000u
#define OFF_CUR2  38680000u
#define OFF_ED2   38710000u
#define OFF_BS2   39220000u
#define OFF_DONE  39230000u    // 2 ints
#define OFF_RK1   39240000u    // E1 ints (edge rank within dst)
#define OFF_RK2   39740000u    // E2 ints -> ends 39,990,000 (~160 MB)

typedef __bf16 bf16x8 __attribute__((ext_vector_type(8)));
typedef float f32x4 __attribute__((ext_vector_type(4)));
typedef float f32x2 __attribute__((ext_vector_type(2)));

static __device__ __forceinline__ float b2f(unsigned short u) {
    union { unsigned int i; float f; } c;
    c.i = ((unsigned int)u) << 16;
    return c.f;
}
// unpack 2 packed bf16 (one dword) -> f32x2 {lo_channel, hi_channel}
static __device__ __forceinline__ f32x2 b2f2(unsigned int u) {
    f32x2 r;
    r.x = __uint_as_float(u << 16);
    r.y = __uint_as_float(u & 0xFFFF0000u);
    return r;
}
static __device__ __forceinline__ unsigned short f2b(float f) {
    unsigned int u = __float_as_uint(f);
    unsigned int r = (u + 0x7fffu + ((u >> 16) & 1u)) >> 16;
    return (unsigned short)r;
}
static __device__ __forceinline__ bf16x8 ldfrag(const unsigned short* p) {
    return *reinterpret_cast<const bf16x8*>(p);
}

// async global->LDS copy, 16B per lane. LDS dest is wave-uniform base
// (HW adds lane*16); global src is per-lane.
static __device__ __forceinline__ void stage16(const void* g, void* l) {
    __builtin_amdgcn_global_load_lds(
        (const __attribute__((address_space(1))) unsigned int*)g,
        (__attribute__((address_space(3))) unsigned int*)l,
        16, 0, 0);
}

// DPP 16-lane reductions
template <int CTRL>
static __device__ __forceinline__ float dpp_addstep(float v) {
    int x = __builtin_amdgcn_mov_dpp(__float_as_int(v), CTRL, 0xF, 0xF, true);
    return v + __int_as_float(x);
}
static __device__ __forceinline__ float red16(float v) {
    v = dpp_addstep<0xB1>(v);
    v = dpp_addstep<0x4E>(v);
    v = dpp_addstep<0x141>(v);
    v = dpp_addstep<0x140>(v);
    return v;
}
template <int CTRL>
static __device__ __forceinline__ float dpp_maxstep(float v) {
    int x = __builtin_amdgcn_mov_dpp(__float_as_int(v), CTRL, 0xF, 0xF, true);
    return fmaxf(v, __int_as_float(x));
}
static __device__ __forceinline__ float red16max(float v) {
    v = dpp_maxstep<0xB1>(v);
    v = dpp_maxstep<0x4E>(v);
    v = dpp_maxstep<0x141>(v);
    v = dpp_maxstep<0x140>(v);
    return v;
}

// ---------------------------------------------------------------------------
// Device GEMM bodies (MFMA 16x16x32 bf16), fragment-linear B.
// B panel staged block-cooperatively into LDS in 4-tile (16 KB) chunks via
// global_load_lds, double-buffered.
// ---------------------------------------------------------------------------
#define LDSS 136
#define SMEM_USHORTS 16384   // 32 KiB: 2 x 16 KiB ping-pong, reused by epilogue

template <int NTILES>
static __device__ __forceinline__ void dev_gemm_bf16out(
    const unsigned short* __restrict__ XB, const unsigned short* __restrict__ WB,
    const float* __restrict__ BP, unsigned short* __restrict__ Y, int n, int blk,
    unsigned short* sb) {
    constexpr int COLS = NTILES * 16;
    constexpr int HALF = NTILES / 2;
    constexpr int HCOLS = HALF * 16;
    constexpr int NCHUNK = (NTILES + 3) / 4;
    int wave = threadIdx.x >> 6, lane = threadIdx.x & 63;
    int m = lane & 15, quad = lane >> 4;
    int rowbase = blk * 64 + wave * 16;
    int arow = rowbase + m; if (arow >= n) arow = n - 1;
    unsigned short* swave = sb + wave * 16 * LDSS;
    const unsigned short* xrow = XB + (size_t)arow * 128 + quad * 8;
    bf16x8 a0 = ldfrag(xrow), a1 = ldfrag(xrow + 32);
    bf16x8 a2 = ldfrag(xrow + 64), a3 = ldfrag(xrow + 96);
    f32x4 acc[NTILES];
#pragma unroll
    for (int t = 0; t < NTILES; t++) acc[t] = (f32x4){0.f, 0.f, 0.f, 0.f};
    const char* gstage = (const char*)WB + wave * 1024 + lane * 16;
#pragma unroll
    for (int i = 0; i < 4; i++)
        stage16(gstage + (size_t)i * 4096, (char*)sb + wave * 1024 + i * 4096);
    __syncthreads();
#pragma unroll
    for (int c = 0; c < NCHUNK; c++) {
        if (c + 1 < NCHUNK) {
            char* lbase = (char*)sb + ((c + 1) & 1) * 16384 + wave * 1024;
#pragma unroll
            for (int i = 0; i < 4; i++)
                if ((c + 1) * 4 + i < NTILES)
                    stage16(gstage + (size_t)((c + 1) * 4 + i) * 4096,
                            lbase + i * 4096);
        }
        const unsigned short* cbase = sb + (c & 1) * 8192;
#pragma unroll
        for (int t = 0; t < 4; t++) {
            int tt = c * 4 + t;
            if (tt < NTILES) {
                const unsigned short* wt = cbase + t * 2048 + lane * 8;
                acc[tt] = __builtin_amdgcn_mfma_f32_16x16x32_bf16(a0, ldfrag(wt), acc[tt], 0, 0, 0);
                acc[tt] = __builtin_amdgcn_mfma_f32_16x16x32_bf16(a1, ldfrag(wt + 512), acc[tt], 0, 0, 0);
                acc[tt] = __builtin_amdgcn_mfma_f32_16x16x32_bf16(a2, ldfrag(wt + 1024), acc[tt], 0, 0, 0);
                acc[tt] = __builtin_amdgcn_mfma_f32_16x16x32_bf16(a3, ldfrag(wt + 1536), acc[tt], 0, 0, 0);
            }
        }
        __syncthreads();
    }
    int tswz_bit = (quad >> 1) & 1;
#pragma unroll
    for (int half = 0; half < 2; half++) {
#pragma unroll
        for (int t = 0; t < HALF; t++) {
            int tt = half * HALF + t;
            int tsw = t ^ tswz_bit;
            float b = BP[tt * 16 + m];
#pragma unroll
            for (int r = 0; r < 4; r++)
                swave[(quad * 4 + r) * LDSS + tsw * 16 + m] = f2b(acc[tt][r] + b);
        }
#pragma unroll
        for (int i = 0; i < 4; i++) {
            int idx = i * 64 + lane;
            int r = idx / (HCOLS / 8), g = idx % (HCOLS / 8);
            int gs = g ^ (((r >> 3) & 1) << 1);
            int grow = rowbase + r;
            if (grow < n) {
                uint4 v = *(const uint4*)&swave[r * LDSS + gs * 8];
                *(uint4*)(Y + (size_t)grow * COLS + half * HCOLS + g * 8) = v;
            }
        }
    }
}

template <int NTILES>
static __device__ __forceinline__ void dev_gemm_f32out(
    const unsigned short* __restrict__ XB, const unsigned short* __restrict__ WB,
    const float* __restrict__ BP, float* __restrict__ Y, int n, int blk,
    unsigned short* sb) {
    constexpr int COLS = NTILES * 16;
    constexpr int NCHUNK = (NTILES + 3) / 4;
    int wave = threadIdx.x >> 6, lane = threadIdx.x & 63;
    int m = lane & 15, quad = lane >> 4;
    int rowbase = blk * 64 + wave * 16;
    int arow = rowbase + m; if (arow >= n) arow = n - 1;
    const unsigned short* xrow = XB + (size_t)arow * 128 + quad * 8;
    bf16x8 a0 = ldfrag(xrow), a1 = ldfrag(xrow + 32);
    bf16x8 a2 = ldfrag(xrow + 64), a3 = ldfrag(xrow + 96);
    f32x4 acc[NTILES];
#pragma unroll
    for (int t = 0; t < NTILES; t++) acc[t] = (f32x4){0.f, 0.f, 0.f, 0.f};
    const char* gstage = (const char*)WB + wave * 1024 + lane * 16;
#pragma unroll
    for (int i = 0; i < 4; i++)
        stage16(gstage + (size_t)i * 4096, (char*)sb + wave * 1024 + i * 4096);
    __syncthreads();
#pragma unroll
    for (int c = 0; c < NCHUNK; c++) {
        if (c + 1 < NCHUNK) {
            char* lbase = (char*)sb + ((c + 1) & 1) * 16384 + wave * 1024;
#pragma unroll
            for (int i = 0; i < 4; i++)
                if ((c + 1) * 4 + i < NTILES)
                    stage16(gstage + (size_t)((c + 1) * 4 + i) * 4096,
                            lbase + i * 4096);
        }
        const unsigned short* cbase = sb + (c & 1) * 8192;
#pragma unroll
        for (int t = 0; t < 4; t++) {
            int tt = c * 4 + t;
            if (tt < NTILES) {
                const unsigned short* wt = cbase + t * 2048 + lane * 8;
                acc[tt] = __builtin_amdgcn_mfma_f32_16x16x32_bf16(a0, ldfrag(wt), acc[tt], 0, 0, 0);
                acc[tt] = __builtin_amdgcn_mfma_f32_16x16x32_bf16(a1, ldfrag(wt + 512), acc[tt], 0, 0, 0);
                acc[tt] = __builtin_amdgcn_mfma_f32_16x16x32_bf16(a2, ldfrag(wt + 1024), acc[tt], 0, 0, 0);
                acc[tt] = __builtin_amdgcn_mfma_f32_16x16x32_bf16(a3, ldfrag(wt + 1536), acc[tt], 0, 0, 0);
            }
        }
        __syncthreads();
    }
#pragma unroll
    for (int t = 0; t < NTILES; t++) {
        float b = BP[t * 16 + m];
#pragma unroll
        for (int r = 0; r < 4; r++) {
            int grow = rowbase + quad * 4 + r;
            if (grow < n) Y[(size_t)grow * COLS + t * 16 + m] = acc[t][r] + b;
        }
    }
}

// ---------------------------------------------------------------------------
// prep
// ---------------------------------------------------------------------------
__global__ __launch_bounds__(256) void prep(
    const float* __restrict__ x, unsigned short* __restrict__ XB,
    const float* __restrict__ Wk1, const float* __restrict__ Wv1,
    const float* __restrict__ Wq1, const float* __restrict__ Wskip1,
    const float* __restrict__ bk1, const float* __restrict__ bv1,
    const float* __restrict__ bq1, const float* __restrict__ bskip1,
    const float* __restrict__ Wk2, const float* __restrict__ Wv2,
    const float* __restrict__ Wq2, const float* __restrict__ Wskip2,
    const float* __restrict__ bk2, const float* __restrict__ bv2,
    const float* __restrict__ bq2, const float* __restrict__ bskip2,
    unsigned short* __restrict__ WB1, float* __restrict__ BP1,
    unsigned short* __restrict__ WB2, float* __restrict__ BP2,
    const float* __restrict__ edge_W, const float* __restrict__ edge_b,
    const float* __restrict__ time_W, const float* __restrict__ time_b,
    const float* __restrict__ We1, const float* __restrict__ We2,
    float* __restrict__ TA1, float* __restrict__ TB1,
    float* __restrict__ TA2, float* __restrict__ TB2,
    int* __restrict__ cnt1, int* __restrict__ cnt2, int* __restrict__ done) {
    int tid = blockIdx.x * blockDim.x + threadIdx.x;
    int stride = gridDim.x * blockDim.x;
    for (int i = tid; i < N0 * 32; i += stride) {
        float4 v = *(const float4*)(x + (size_t)i * 4);
        ushort4 u;
        u.x = f2b(v.x); u.y = f2b(v.y); u.z = f2b(v.z); u.w = f2b(v.w);
        *(ushort4*)(XB + (size_t)i * 4) = u;
    }
    for (int i = tid; i < 512 * 128; i += stride) {
        int j = i & 7, l = (i >> 3) & 63, ks = (i >> 9) & 3, t = i >> 11;
        int row = t * 16 + (l & 15);
        int col = ks * 32 + ((l >> 4) & 3) * 8 + j;
        const float* w; int off;
        if (row < 128) { w = Wk1; off = 0; }
        else if (row < 256) { w = Wv1; off = 128; }
        else if (row < 384) { w = Wq1; off = 256; }
        else { w = Wskip1; off = 384; }
        WB1[i] = f2b(w[(size_t)(row - off) * 128 + col]);
    }
    for (int i = tid; i < 512; i += stride) {
        const float* b; int off;
        if (i < 128) { b = bk1; off = 0; }
        else if (i < 256) { b = bv1; off = 128; }
        else if (i < 384) { b = bq1; off = 256; }
        else { b = bskip1; off = 384; }
        BP1[i] = b[i - off];
    }
    for (int i = tid; i < 448 * 128; i += stride) {
        int j = i & 7, l = (i >> 3) & 63, ks = (i >> 9) & 3, t = i >> 11;
        int row = t * 16 + (l & 15);
        int col = ks * 32 + ((l >> 4) & 3) * 8 + j;
        const float* w; int off;
        if (row < 128) { w = Wk2; off = 0; }
        else if (row < 256) { w = Wv2; off = 128; }
        else if (row < 384) { w = Wq2; off = 256; }
        else { w = Wskip2; off = 384; }
        WB2[i] = f2b(w[(size_t)(row - off) * 128 + col]);
    }
    for (int i = tid; i < 448; i += stride) {
        const float* b; int off;
        if (i < 128) { b = bk2; off = 0; }
        else if (i < 256) { b = bv2; off = 128; }
        else if (i < 384) { b = bq2; off = 256; }
        else { b = bskip2; off = 384; }
        BP2[i] = b[i - off];
    }
    const int TBL = (NTYPE + NTS) * 128;
    for (int i = tid; i < TBL; i += stride) {
        if (i < NTYPE * 128) {
            int e = i >> 7, c = i & 127;
            float s1 = 0.f, s2 = 0.f;
#pragma unroll
            for (int j = 0; j < 10; j++) {
                float fj = edge_W[j * NTYPE + e] + edge_b[j];
                s1 += fj * We1[c * 20 + j];
                s2 += fj * We2[c * 20 + j];
            }
            TA1[i] = s1; TA2[i] = s2;
        } else {
            int u = i - NTYPE * 128;
            int ts = u >> 7, c = u & 127;
            float s1 = 0.f, s2 = 0.f;
#pragma unroll
            for (int j = 0; j < 10; j++) {
                float fj = time_W[j * NTS + ts] + time_b[j];
                s1 += fj * We1[c * 20 + 10 + j];
                s2 += fj * We2[c * 20 + 10 + j];
            }
            TB1[u] = s1; TB2[u] = s2;
        }
    }
    for (int i = tid; i < N1 + N2 + 2; i += stride) {
        if (i < N1) cnt1[i] = 0;
        else if (i < N1 + N2) cnt2[i - N1] = 0;
        else done[i - N1 - N2] = 0;
    }
}

// ---------------------------------------------------------------------------
// mega_l1: degree count FIRST (atomic drain overlaps GEMM), then KV1 GEMM,
// then QR1 GEMM.
// ---------------------------------------------------------------------------
__global__ __launch_bounds__(256) void mega_l1(
    const unsigned short* __restrict__ XB,
    const unsigned short* __restrict__ WB1, const float* __restrict__ BP1,
    unsigned short* __restrict__ KV1, float* __restrict__ QR1,
    const int* __restrict__ d1, const int* __restrict__ d2,
    int* __restrict__ cnt1, int* __restrict__ cnt2,
    int* __restrict__ rk1, int* __restrict__ rk2) {
    __shared__ __align__(16) unsigned short sbuf[SMEM_USHORTS];
    int b = blockIdx.x;
    if (b < CNTB) {
        int t = b * 256 + threadIdx.x;
        if (t < E1C) rk1[t] = atomicAdd(&cnt1[d1[t]], 1);
        else {
            t -= E1C;
            if (t < E2C) rk2[t] = atomicAdd(&cnt2[d2[t]], 1);
        }
    } else if (b < CNTB + KV1B) {
        dev_gemm_bf16out<16>(XB, WB1, BP1, KV1, N0, b - CNTB, sbuf);
    } else {
        dev_gemm_f32out<16>(XB, WB1 + 256 * 128, BP1 + 256, QR1, N1,
                            b - CNTB - KV1B, sbuf);
    }
}

__global__ __launch_bounds__(256) void gemm_l2(
    const unsigned short* __restrict__ H,
    const unsigned short* __restrict__ WB2, const float* __restrict__ BP2,
    unsigned short* __restrict__ KV2, float* __restrict__ QR2) {
    __shared__ __align__(16) unsigned short sbuf[SMEM_USHORTS];
    int b = blockIdx.x;
    if (b < KV2B) dev_gemm_bf16out<16>(H, WB2, BP2, KV2, N1, b, sbuf);
    else dev_gemm_f32out<12>(H, WB2 + 256 * 128, BP2 + 256, QR2, N2, b - KV2B, sbuf);
}

// ---------------------------------------------------------------------------
// csr_scan + TC-build: first NB1+NB2 blocks do the scan (device barrier
// among themselves only); extra TCB blocks build the combined bf16 edge
// tables TC[tidx][c] = TA[t][c] + TB[ts][c], tidx = t*NTS+ts. The build
// blocks never touch done/bs, and they terminate, so the scan's spin-wait
// cannot deadlock.
// ---------------------------------------------------------------------------
__global__ __launch_bounds__(256) void csr_scan(
    int* __restrict__ cnt1, int* __restrict__ bs1, int* __restrict__ rp1,
    int* __restrict__ cnt2, int* __restrict__ bs2, int* __restrict__ rp2,
    int* __restrict__ done,
    const float* __restrict__ TA1, const float* __restrict__ TB1,
    const float* __restrict__ TA2, const float* __restrict__ TB2,
    unsigned short* __restrict__ TC1, unsigned short* __restrict__ TC2) {
    int b = blockIdx.x;
    if (b >= NB1 + NB2) {
        const int UNITS = NTC * 16;  // ushort8 units per table
        int bid = b - (NB1 + NB2);
        for (int i = bid * 256 + threadIdx.x; i < 2 * UNITS; i += TCB * 256) {
            int tab = (i >= UNITS);
            int j = tab ? i - UNITS : i;
            int tidx = j >> 4, c8 = (j & 15) << 3;
            int t = tidx / NTS, ts = tidx - t * NTS;
            const float* ta = (tab ? TA2 : TA1) + t * 128 + c8;
            const float* tb = (tab ? TB2 : TB1) + ts * 128 + c8;
            unsigned short* o = (tab ? TC2 : TC1) + (size_t)tidx * 128 + c8;
            float4 a0 = *(const float4*)ta, a1 = *(const float4*)(ta + 4);
            float4 b0 = *(const float4*)tb, b1 = *(const float4*)(tb + 4);
            ushort4 o0, o1;
            o0.x = f2b(a0.x + b0.x); o0.y = f2b(a0.y + b0.y);
            o0.z = f2b(a0.z + b0.z); o0.w = f2b(a0.w + b0.w);
            o1.x = f2b(a1.x + b1.x); o1.y = f2b(a1.y + b1.y);
            o1.z = f2b(a1.z + b1.z); o1.w = f2b(a1.w + b1.w);
            *(ushort4*)o = o0; *(ushort4*)(o + 4) = o1;
        }
        return;
    }
    __shared__ int s[256];
    __shared__ int amlast;
    int* cnt; int* bs; int* rp; int n, lb;
    if (b < NB1) { cnt = cnt1; bs = bs1; rp = rp1; n = N1; lb = b; }
    else { cnt = cnt2; bs = bs2; rp = rp2; n = N2; lb = b - NB1; }
    int t = lb * 256 + threadIdx.x;
    int v = (t < n) ? cnt[t] : 0;
    s[threadIdx.x] = v;
    __syncthreads();
    for (int off = 128; off; off >>= 1) {
        if (threadIdx.x < off) s[threadIdx.x] += s[threadIdx.x + off];
        __syncthreads();
    }
    if (threadIdx.x == 0) {
        atomicExch(&bs[lb], s[0]);
        __threadfence();
        int prev = atomicAdd(&done[0], 1);
        amlast = (prev == NB1 + NB2 - 1) ? 1 : 0;
    }
    __syncthreads();
    if (amlast) {
        int tt = threadIdx.x;
        int v1 = (tt < NB1) ? atomicAdd(&bs1[tt], 0) : 0;
        s[tt] = v1;
        __syncthreads();
        for (int off = 1; off < 256; off <<= 1) {
            int u = (tt >= off) ? s[tt - off] : 0;
            __syncthreads();
            s[tt] += u;
            __syncthreads();
        }
        if (tt < NB1) atomicExch(&bs1[tt], s[tt] - v1);
        __syncthreads();
        int v2 = (tt < NB2) ? atomicAdd(&bs2[tt], 0) : 0;
        s[tt] = v2;
        __syncthreads();
        for (int off = 1; off < 256; off <<= 1) {
            int u = (tt >= off) ? s[tt - off] : 0;
            __syncthreads();
            s[tt] += u;
            __syncthreads();
        }
        if (tt < NB2) atomicExch(&bs2[tt], s[tt] - v2);
        __threadfence();
        __syncthreads();
        if (tt == 0) atomicExch(&done[1], 1);
    }
    if (threadIdx.x == 0) {
        while (atomicAdd(&done[1], 0) == 0) __builtin_amdgcn_s_sleep(1);
    }
    __syncthreads();
    __threadfence();
    int base = atomicAdd(&bs[lb], 0);
    s[threadIdx.x] = v;
    __syncthreads();
    for (int off = 1; off < 256; off <<= 1) {
        int u = (threadIdx.x >= off) ? s[threadIdx.x - off] : 0;
        __syncthreads();
        s[threadIdx.x] += u;
        __syncthreads();
    }
    int incl = s[threadIdx.x];
    if (t < n) rp[t] = base + incl - v;
    if (t == n - 1) rp[n] = base + incl;
}

// ---------------------------------------------------------------------------
// fill_both: atomic-free scatter; ed.y = combined TC row ELEMENT offset
// ---------------------------------------------------------------------------
__global__ __launch_bounds__(256) void fill_both(
    const int* __restrict__ d1, const int* __restrict__ s1,
    const int* __restrict__ et1, const int* __restrict__ ets1,
    const int* __restrict__ rp1, const int* __restrict__ rk1, uint2* __restrict__ ed1,
    const int* __restrict__ d2, const int* __restrict__ s2,
    const int* __restrict__ et2, const int* __restrict__ ets2,
    const int* __restrict__ rp2, const int* __restrict__ rk2, uint2* __restrict__ ed2) {
    int t = blockIdx.x * 256 + threadIdx.x;
    if (t < E1C) {
        int pos = rp1[d1[t]] + rk1[t];
        ed1[pos] = make_uint2((unsigned)s1[t],
                              (unsigned)((et1[t] * NTS + ets1[t]) * 128));
    } else {
        t -= E1C;
        if (t < E2C) {
            int pos = rp2[d2[t]] + rk2[t];
            ed2[pos] = make_uint2((unsigned)s2[t],
                                  (unsigned)((et2[t] * NTS + ets2[t]) * 128));
        }
    }
}

// ---------------------------------------------------------------------------
// Fused aggregation (round-1 rotation pipeline + packed f32x2 math + single
// combined bf16 TC gather: 768 B/edge instead of 1536 B, ~25% fewer VALU).
// ---------------------------------------------------------------------------
static __device__ __forceinline__ void edge_accum(
    int beg, int end, int s, int co, f32x2 q01, f32x2 q23,
    const uint2* __restrict__ ED, const unsigned short* __restrict__ TCl,
    const unsigned short* __restrict__ KV,
    f32x2& acc01, f32x2& acc23, float& suma) {
    int p = beg + s;
    if (p >= end) return;
    uint2 d0 = ED[p];
    int pA = p + 2;  bool mA = pA < end;
    uint2 d1 = ED[mA ? pA : beg];
    int pB = p + 4;  bool mB = pB < end;
    uint2 d2 = ED[mB ? pB : beg];
    uint2 tc0 = *(const uint2*)(TCl + d0.y);
    const unsigned short* kv0 = KV + (size_t)d0.x * 256;
    uint2 ku0 = *(const uint2*)(kv0 + co);
    uint2 vu0 = *(const uint2*)(kv0 + 128 + co);
    uint2 tc1 = *(const uint2*)(TCl + d1.y);
    const unsigned short* kv1 = KV + (size_t)d1.x * 256;
    uint2 ku1 = *(const uint2*)(kv1 + co);
    uint2 vu1 = *(const uint2*)(kv1 + 128 + co);
    for (;;) {
        int pC = pB + 2; bool mC = pC < end;
        uint2 d3 = ED[mC ? pC : beg];
        uint2 tc2 = *(const uint2*)(TCl + d2.y);
        const unsigned short* kv2 = KV + (size_t)d2.x * 256;
        uint2 ku2 = *(const uint2*)(kv2 + co);
        uint2 vu2 = *(const uint2*)(kv2 + 128 + co);
        f32x2 e01 = b2f2(tc0.x), e23 = b2f2(tc0.y);
        f32x2 k01 = b2f2(ku0.x) + e01, k23 = b2f2(ku0.y) + e23;
        f32x2 pp2 = q01 * k01 + q23 * k23;
        float pp = pp2.x + pp2.y;
        pp = red16(pp);
        float a = __expf(pp * 0.125f);
        f32x2 v01 = b2f2(vu0.x) + e01, v23 = b2f2(vu0.y) + e23;
        f32x2 av = {a, a};
        acc01 += av * v01; acc23 += av * v23;
        suma += a;
        if (!mA) break;
        tc0 = tc1; ku0 = ku1; vu0 = vu1;
        tc1 = tc2; ku1 = ku2; vu1 = vu2;
        d2 = d3;
        mA = mB; mB = mC; pB = pC;
    }
}

__global__ __launch_bounds__(256) void agg_layer1(
    const int* __restrict__ rowptr, const uint2* __restrict__ ED,
    const unsigned short* __restrict__ TC,
    const float* __restrict__ QR, const unsigned short* __restrict__ KV,
    const float* __restrict__ Wbeta,
    const float* __restrict__ ln_g, const float* __restrict__ ln_b,
    unsigned short* __restrict__ hout, int n) {
    int wid = (blockIdx.x * blockDim.x + threadIdx.x) >> 6;
    int lane = threadIdx.x & 63;
    if (wid >= n) return;
    int s = lane >> 5, cg = lane & 15;
    int co = ((lane >> 4) & 1) * 64 + 4 * cg;
    int beg = rowptr[wid], end = rowptr[wid + 1];
    float4 q4 = *(const float4*)(QR + (size_t)wid * 256 + co);
    f32x2 q01 = {q4.x, q4.y}, q23 = {q4.z, q4.w};
    f32x2 acc01 = {0.f, 0.f}, acc23 = {0.f, 0.f};
    float suma = 0.f;
    edge_accum(beg, end, s, co, q01, q23, ED, TC + co, KV, acc01, acc23, suma);
    float ax = acc01.x, ay = acc01.y, az = acc23.x, aw = acc23.y;
    ax += __shfl_xor(ax, 32); ay += __shfl_xor(ay, 32);
    az += __shfl_xor(az, 32); aw += __shfl_xor(aw, 32);
    suma += __shfl_xor(suma, 32);
    float inv_s = 1.f / (suma + 1e-16f);
    float ox = ax * inv_s, oy = ay * inv_s, oz = az * inv_s, ow = aw * inv_s;
    float4 r4 = *(const float4*)(QR + (size_t)wid * 256 + 128 + co);
    float4 wo = *(const float4*)(Wbeta + co);
    float4 wr = *(const float4*)(Wbeta + 128 + co);
    float4 wd = *(const float4*)(Wbeta + 256 + co);
    float pb = wo.x * ox + wr.x * r4.x + wd.x * (ox - r4.x)
             + wo.y * oy + wr.y * r4.y + wd.y * (oy - r4.y)
             + wo.z * oz + wr.z * r4.z + wd.z * (oz - r4.z)
             + wo.w * ow + wr.w * r4.w + wd.w * (ow - r4.w);
    pb = red16(pb);
    pb += __shfl_xor(pb, 16);
    float beta = 1.f / (1.f + __expf(-pb));
    float gx = beta * r4.x + (1.f - beta) * ox;
    float gy = beta * r4.y + (1.f - beta) * oy;
    float gz = beta * r4.z + (1.f - beta) * oz;
    float gw = beta * r4.w + (1.f - beta) * ow;
    float sm = gx + gy + gz + gw;
    float sq = gx * gx + gy * gy + gz * gz + gw * gw;
    sm = red16(sm); sm += __shfl_xor(sm, 16);
    sq = red16(sq); sq += __shfl_xor(sq, 16);
    float mu = sm * (1.f / 128.f);
    float var = sq * (1.f / 128.f) - mu * mu;
    float inv = rsqrtf(var + 1e-5f);
    float4 lg = *(const float4*)(ln_g + co);
    float4 lb = *(const float4*)(ln_b + co);
    float yx = (gx - mu) * inv * lg.x + lb.x;
    float yy = (gy - mu) * inv * lg.y + lb.y;
    float yz = (gz - mu) * inv * lg.z + lb.z;
    float yw = (gw - mu) * inv * lg.w + lb.w;
    const float ISQ2 = 0.70710678118654752f;
    yx = 0.5f * yx * (1.f + erff(yx * ISQ2));
    yy = 0.5f * yy * (1.f + erff(yy * ISQ2));
    yz = 0.5f * yz * (1.f + erff(yz * ISQ2));
    yw = 0.5f * yw * (1.f + erff(yw * ISQ2));
    if (s == 0) {
        ushort4 hv;
        hv.x = f2b(yx); hv.y = f2b(yy); hv.z = f2b(yz); hv.w = f2b(yw);
        *(ushort4*)(hout + (size_t)wid * 128 + co) = hv;
    }
}

__global__ __launch_bounds__(256) void agg_layer2(
    const int* __restrict__ rowptr, const uint2* __restrict__ ED,
    const unsigned short* __restrict__ TC,
    const float* __restrict__ QR, const unsigned short* __restrict__ KV,
    const float* __restrict__ Wbeta,
    float* __restrict__ o, int n) {
    int wid = (blockIdx.x * blockDim.x + threadIdx.x) >> 6;
    int lane = threadIdx.x & 63;
    if (wid >= n) return;
    int s = lane >> 5, cg = lane & 15;
    int co = ((lane >> 4) & 1) * 64 + 4 * cg;
    int beg = rowptr[wid], end = rowptr[wid + 1];
    float4 q4 = *(const float4*)(QR + (size_t)wid * 192 + co);
    f32x2 q01 = {q4.x, q4.y}, q23 = {q4.z, q4.w};
    f32x2 acc01 = {0.f, 0.f}, acc23 = {0.f, 0.f};
    float suma = 0.f;
    edge_accum(beg, end, s, co, q01, q23, ED, TC + co, KV, acc01, acc23, suma);
    float ax = acc01.x, ay = acc01.y, az = acc23.x, aw = acc23.y;
    ax += __shfl_xor(ax, 32); ay += __shfl_xor(ay, 32);
    az += __shfl_xor(az, 32); aw += __shfl_xor(aw, 32);
    suma += __shfl_xor(suma, 32);
    float inv_s = 1.f / (suma + 1e-16f);
    float ox = ax * inv_s, oy = ay * inv_s, oz = az * inv_s, ow = aw * inv_s;
    ox = 0.5f * (ox + __shfl_xor(ox, 16));
    oy = 0.5f * (oy + __shfl_xor(oy, 16));
    oz = 0.5f * (oz + __shfl_xor(oz, 16));
    ow = 0.5f * (ow + __shfl_xor(ow, 16));
    float4 r4 = *(const float4*)(QR + (size_t)wid * 192 + 128 + 4 * cg);
    float4 wo = *(const float4*)(Wbeta + 4 * cg);
    float4 wr = *(const float4*)(Wbeta + 64 + 4 * cg);
    float4 wd = *(const float4*)(Wbeta + 128 + 4 * cg);
    float pb = wo.x * ox + wr.x * r4.x + wd.x * (ox - r4.x)
             + wo.y * oy + wr.y * r4.y + wd.y * (oy - r4.y)
             + wo.z * oz + wr.z * r4.z + wd.z * (oz - r4.z)
             + wo.w * ow + wr.w * r4.w + wd.w * (ow - r4.w);
    pb = red16(pb);
    float beta = 1.f / (1.f + __expf(-pb));
    float vx = beta * r4.x + (1.f - beta) * ox;
    float vy = beta * r4.y + (1.f - beta) * oy;
    float vz = beta * r4.z + (1.f - beta) * oz;
    float vw = beta * r4.w + (1.f - beta) * ow;
    float m = fmaxf(fmaxf(vx, vy), fmaxf(vz, vw));
    m = red16max(m);
    float se = __expf(vx - m) + __expf(vy - m) + __expf(vz - m) + __expf(vw - m);
    se = red16(se);
    float lse = m + logf(se);
    if (lane < 16)
        *(float4*)(o + (size_t)wid * 64 + 4 * cg) =
            make_float4(vx - lse, vy - lse, vz - lse, vw - lse);
}

extern "C" void kernel_launch(void* const* d_in, const int* in_sizes, int n_in,
                              void* d_out, int out_size, void* d_ws, size_t ws_size,
                              hipStream_t stream) {
    const float* x        = (const float*)d_in[0];
    const int*   ei1_src  = (const int*)d_in[1];
    const int*   ei1_dst  = (const int*)d_in[2];
    const int*   et1      = (const int*)d_in[3];
    const int*   ets1     = (const int*)d_in[4];
    const int*   ei2_src  = (const int*)d_in[5];
    const int*   ei2_dst  = (const int*)d_in[6];
    const int*   et2      = (const int*)d_in[7];
    const int*   ets2     = (const int*)d_in[8];
    const float* edge_W   = (const float*)d_in[9];
    const float* edge_b   = (const float*)d_in[10];
    const float* time_W   = (const float*)d_in[11];
    const float* time_b   = (const float*)d_in[12];
    const float* Wq1      = (const float*)d_in[13];
    const float* bq1      = (const float*)d_in[14];
    const float* Wk1      = (const float*)d_in[15];
    const float* bk1      = (const float*)d_in[16];
    const float* Wv1      = (const float*)d_in[17];
    const float* bv1      = (const float*)d_in[18];
    const float* We1      = (const float*)d_in[19];
    const float* Wskip1   = (const float*)d_in[20];
    const float* bskip1   = (const float*)d_in[21];
    const float* Wbeta1   = (const float*)d_in[22];
    const float* ln_g     = (const float*)d_in[23];
    const float* ln_b     = (const float*)d_in[24];
    const float* Wq2      = (const float*)d_in[25];
    const float* bq2      = (const float*)d_in[26];
    const float* Wk2      = (const float*)d_in[27];
    const float* bk2      = (const float*)d_in[28];
    const float* Wv2      = (const float*)d_in[29];
    const float* bv2      = (const float*)d_in[30];
    const float* We2      = (const float*)d_in[31];
    const float* Wskip2   = (const float*)d_in[32];
    const float* bskip2   = (const float*)d_in[33];
    const float* Wbeta2   = (const float*)d_in[34];

    float* ws = (float*)d_ws;
    unsigned short* xb  = (unsigned short*)(ws + OFF_XB);
    unsigned short* tc1 = (unsigned short*)(ws + OFF_TC1);
    unsigned short* tc2 = (unsigned short*)(ws + OFF_TC2);
    float* qr1          = ws + OFF_QR1;
    unsigned short* kv1 = (unsigned short*)(ws + OFF_KV1);
    unsigned short* h   = (unsigned short*)(ws + OFF_H);
    float* qr2          = ws + OFF_QR2;
    unsigned short* kv2 = (unsigned short*)(ws + OFF_KV2);
    unsigned short* wb1 = (unsigned short*)(ws + OFF_WB1);
    float* bp1          = ws + OFF_BP1;
    unsigned short* wb2 = (unsigned short*)(ws + OFF_WB2);
    float* bp2          = ws + OFF_BP2;
    float* ta1          = ws + OFF_TA1;
    float* tb1          = ws + OFF_TB1;
    float* ta2          = ws + OFF_TA2;
    float* tb2          = ws + OFF_TB2;
    int*   rp1          = (int*)(ws + OFF_RP1);
    int*   cur1         = (int*)(ws + OFF_CUR1);
    uint2* ed1          = (uint2*)(ws + OFF_ED1);
    int*   bs1          = (int*)(ws + OFF_BS1);
    int*   rp2          = (int*)(ws + OFF_RP2);
    int*   cur2         = (int*)(ws + OFF_CUR2);
    uint2* ed2          = (uint2*)(ws + OFF_ED2);
    int*   bs2          = (int*)(ws + OFF_BS2);
    int*   done         = (int*)(ws + OFF_DONE);
    int*   rk1          = (int*)(ws + OFF_RK1);
    int*   rk2          = (int*)(ws + OFF_RK2);

    prep<<<2048, 256, 0, stream>>>(
        x, xb,
        Wk1, Wv1, Wq1, Wskip1, bk1, bv1, bq1, bskip1,
        Wk2, Wv2, Wq2, Wskip2, bk2, bv2, bq2, bskip2,
        wb1, bp1, wb2, bp2,
        edge_W, edge_b, time_W, time_b, We1, We2,
        ta1, tb1, ta2, tb2, cur1, cur2, done);
    mega_l1<<<KV1B + QR1B + CNTB, 256, 0, stream>>>(
        xb, wb1, bp1, kv1, qr1, ei1_dst, ei2_dst, cur1, cur2, rk1, rk2);
    csr_scan<<<NB1 + NB2 + TCB, 256, 0, stream>>>(
        cur1, bs1, rp1, cur2, bs2, rp2, done,
        ta1, tb1, ta2, tb2, tc1, tc2);
    fill_both<<<FILLB, 256, 0, stream>>>(
        ei1_dst, ei1_src, et1, ets1, rp1, rk1, ed1,
        ei2_dst, ei2_src, et2, ets2, rp2, rk2, ed2);
    agg_layer1<<<(N1 + 3) / 4, 256, 0, stream>>>(rp1, ed1,
        tc1, qr1, kv1, Wbeta1, ln_g, ln_b, h, N1);
    gemm_l2<<<KV2B + QR2B, 256, 0, stream>>>(h, wb2, bp2, kv2, qr2);
    agg_layer2<<<(N2 + 3) / 4, 256, 0, stream>>>(rp2, ed2,
        tc2, qr2, kv2, Wbeta2, (float*)d_out, N2);
}

// Round 6
// 371.928 us; speedup vs baseline: 1.0047x; 1.0047x over previous
//
#include <hip/hip_runtime.h>
#include <math.h>

// Problem constants
#define N0 80000
#define N1 40000
#define N2 20000
#define E1C 500000
#define E2C 250000
#define NTYPE 23
#define NTS 1158

// derived grid constants
#define NB1 157
#define NB2 79
#define KV1B 1250
#define QR1B 625
#define CNTB 2930
#define KV2B 625
#define QR2B 313
#define FILLB 2930

// ---------------- Workspace layout (float offsets) ----------------
#define OFF_XB    0u
#define OFF_QR1   5120000u
#define OFF_KV1   15360000u
#define OFF_H     25600000u
#define OFF_QR2   28160000u
#define OFF_KV2   32000000u
#define OFF_WB1   37120000u
#define OFF_BP1   37160000u
#define OFF_WB2   37170000u
#define OFF_BP2   37200000u
#define OFF_TA1   37210000u
#define OFF_TB1   37213000u
#define OFF_TA2   37370000u
#define OFF_TB2   37373000u
#define OFF_RP1   37530000u
#define OFF_CUR1  37580000u
#define OFF_ED1   37630000u
#define OFF_BS1   38640000u
#define OFF_RP2   38650000u
#define OFF_CUR2  38680000u
#define OFF_ED2   38710000u
#define OFF_BS2   39220000u
#define OFF_DONE  39230000u    // 2 ints
#define OFF_RK1   39240000u    // E1 ints (edge rank within dst)
#define OFF_RK2   39740000u    // E2 ints -> ends 39,990,000 (~160 MB)

typedef __bf16 bf16x8 __attribute__((ext_vector_type(8)));
typedef float f32x4 __attribute__((ext_vector_type(4)));
typedef float f32x2 __attribute__((ext_vector_type(2)));

static __device__ __forceinline__ float b2f(unsigned short u) {
    union { unsigned int i; float f; } c;
    c.i = ((unsigned int)u) << 16;
    return c.f;
}
// unpack 2 packed bf16 (one dword) -> f32x2 {lo_channel, hi_channel}
static __device__ __forceinline__ f32x2 b2f2(unsigned int u) {
    f32x2 r;
    r.x = __uint_as_float(u << 16);
    r.y = __uint_as_float(u & 0xFFFF0000u);
    return r;
}
static __device__ __forceinline__ unsigned short f2b(float f) {
    unsigned int u = __float_as_uint(f);
    unsigned int r = (u + 0x7fffu + ((u >> 16) & 1u)) >> 16;
    return (unsigned short)r;
}
static __device__ __forceinline__ bf16x8 ldfrag(const unsigned short* p) {
    return *reinterpret_cast<const bf16x8*>(p);
}

// async global->LDS copy, 16B per lane. LDS dest is wave-uniform base
// (HW adds lane*16); global src is per-lane.
static __device__ __forceinline__ void stage16(const void* g, void* l) {
    __builtin_amdgcn_global_load_lds(
        (const __attribute__((address_space(1))) unsigned int*)g,
        (__attribute__((address_space(3))) unsigned int*)l,
        16, 0, 0);
}

// DPP reductions. red16 = butterfly over a 16-lane DPP row;
// red8 = butterfly over each 8-lane half-row (3 steps).
template <int CTRL>
static __device__ __forceinline__ float dpp_addstep(float v) {
    int x = __builtin_amdgcn_mov_dpp(__float_as_int(v), CTRL, 0xF, 0xF, true);
    return v + __int_as_float(x);
}
static __device__ __forceinline__ float red16(float v) {
    v = dpp_addstep<0xB1>(v);
    v = dpp_addstep<0x4E>(v);
    v = dpp_addstep<0x141>(v);
    v = dpp_addstep<0x140>(v);
    return v;
}
static __device__ __forceinline__ float red8(float v) {
    v = dpp_addstep<0xB1>(v);
    v = dpp_addstep<0x4E>(v);
    v = dpp_addstep<0x141>(v);
    return v;
}
template <int CTRL>
static __device__ __forceinline__ float dpp_maxstep(float v) {
    int x = __builtin_amdgcn_mov_dpp(__float_as_int(v), CTRL, 0xF, 0xF, true);
    return fmaxf(v, __int_as_float(x));
}
static __device__ __forceinline__ float red8max(float v) {
    v = dpp_maxstep<0xB1>(v);
    v = dpp_maxstep<0x4E>(v);
    v = dpp_maxstep<0x141>(v);
    return v;
}

// ---------------------------------------------------------------------------
// Device GEMM bodies (MFMA 16x16x32 bf16), fragment-linear B. 8-tile (32 KB)
// block-cooperative LDS staging via global_load_lds (round-1 measured best).
// ---------------------------------------------------------------------------
#define LDSS 136
#define SMEM_USHORTS 16384   // 32 KiB: B-chunk staging, reused by epilogue

template <int NTILES>
static __device__ __forceinline__ void dev_gemm_bf16out(
    const unsigned short* __restrict__ XB, const unsigned short* __restrict__ WB,
    const float* __restrict__ BP, unsigned short* __restrict__ Y, int n, int blk,
    unsigned short* sb) {
    constexpr int COLS = NTILES * 16;
    constexpr int HALF = NTILES / 2;
    constexpr int HCOLS = HALF * 16;
    constexpr int NCHUNK = (NTILES + 7) / 8;
    int wave = threadIdx.x >> 6, lane = threadIdx.x & 63;
    int m = lane & 15, quad = lane >> 4;
    int rowbase = blk * 64 + wave * 16;
    int arow = rowbase + m; if (arow >= n) arow = n - 1;
    unsigned short* swave = sb + wave * 16 * LDSS;
    const unsigned short* xrow = XB + (size_t)arow * 128 + quad * 8;
    bf16x8 a0 = ldfrag(xrow), a1 = ldfrag(xrow + 32);
    bf16x8 a2 = ldfrag(xrow + 64), a3 = ldfrag(xrow + 96);
    f32x4 acc[NTILES];
#pragma unroll
    for (int t = 0; t < NTILES; t++) acc[t] = (f32x4){0.f, 0.f, 0.f, 0.f};
    const char* gstage = (const char*)WB + wave * 1024 + lane * 16;
    char* lstage = (char*)sb + wave * 1024;
#pragma unroll
    for (int c = 0; c < NCHUNK; c++) {
#pragma unroll
        for (int i = 0; i < 8; i++)
            if (c * 8 + i < NTILES)
                stage16(gstage + (size_t)(c * 8 + i) * 4096, lstage + i * 4096);
        __syncthreads();
#pragma unroll
        for (int t = 0; t < 8; t++) {
            if (c * 8 + t < NTILES) {
                int tt = c * 8 + t;
                const unsigned short* wt = sb + t * 2048 + lane * 8;
                acc[tt] = __builtin_amdgcn_mfma_f32_16x16x32_bf16(a0, ldfrag(wt), acc[tt], 0, 0, 0);
                acc[tt] = __builtin_amdgcn_mfma_f32_16x16x32_bf16(a1, ldfrag(wt + 512), acc[tt], 0, 0, 0);
                acc[tt] = __builtin_amdgcn_mfma_f32_16x16x32_bf16(a2, ldfrag(wt + 1024), acc[tt], 0, 0, 0);
                acc[tt] = __builtin_amdgcn_mfma_f32_16x16x32_bf16(a3, ldfrag(wt + 1536), acc[tt], 0, 0, 0);
            }
        }
        __syncthreads();
    }
    int tswz_bit = (quad >> 1) & 1;
#pragma unroll
    for (int half = 0; half < 2; half++) {
#pragma unroll
        for (int t = 0; t < HALF; t++) {
            int tt = half * HALF + t;
            int tsw = t ^ tswz_bit;
            float b = BP[tt * 16 + m];
#pragma unroll
            for (int r = 0; r < 4; r++)
                swave[(quad * 4 + r) * LDSS + tsw * 16 + m] = f2b(acc[tt][r] + b);
        }
#pragma unroll
        for (int i = 0; i < 4; i++) {
            int idx = i * 64 + lane;
            int r = idx / (HCOLS / 8), g = idx % (HCOLS / 8);
            int gs = g ^ (((r >> 3) & 1) << 1);
            int grow = rowbase + r;
            if (grow < n) {
                uint4 v = *(const uint4*)&swave[r * LDSS + gs * 8];
                *(uint4*)(Y + (size_t)grow * COLS + half * HCOLS + g * 8) = v;
            }
        }
    }
}

template <int NTILES>
static __device__ __forceinline__ void dev_gemm_f32out(
    const unsigned short* __restrict__ XB, const unsigned short* __restrict__ WB,
    const float* __restrict__ BP, float* __restrict__ Y, int n, int blk,
    unsigned short* sb) {
    constexpr int COLS = NTILES * 16;
    constexpr int NCHUNK = (NTILES + 7) / 8;
    int wave = threadIdx.x >> 6, lane = threadIdx.x & 63;
    int m = lane & 15, quad = lane >> 4;
    int rowbase = blk * 64 + wave * 16;
    int arow = rowbase + m; if (arow >= n) arow = n - 1;
    const unsigned short* xrow = XB + (size_t)arow * 128 + quad * 8;
    bf16x8 a0 = ldfrag(xrow), a1 = ldfrag(xrow + 32);
    bf16x8 a2 = ldfrag(xrow + 64), a3 = ldfrag(xrow + 96);
    f32x4 acc[NTILES];
#pragma unroll
    for (int t = 0; t < NTILES; t++) acc[t] = (f32x4){0.f, 0.f, 0.f, 0.f};
    const char* gstage = (const char*)WB + wave * 1024 + lane * 16;
    char* lstage = (char*)sb + wave * 1024;
#pragma unroll
    for (int c = 0; c < NCHUNK; c++) {
#pragma unroll
        for (int i = 0; i < 8; i++)
            if (c * 8 + i < NTILES)
                stage16(gstage + (size_t)(c * 8 + i) * 4096, lstage + i * 4096);
        __syncthreads();
#pragma unroll
        for (int t = 0; t < 8; t++) {
            if (c * 8 + t < NTILES) {
                int tt = c * 8 + t;
                const unsigned short* wt = sb + t * 2048 + lane * 8;
                acc[tt] = __builtin_amdgcn_mfma_f32_16x16x32_bf16(a0, ldfrag(wt), acc[tt], 0, 0, 0);
                acc[tt] = __builtin_amdgcn_mfma_f32_16x16x32_bf16(a1, ldfrag(wt + 512), acc[tt], 0, 0, 0);
                acc[tt] = __builtin_amdgcn_mfma_f32_16x16x32_bf16(a2, ldfrag(wt + 1024), acc[tt], 0, 0, 0);
                acc[tt] = __builtin_amdgcn_mfma_f32_16x16x32_bf16(a3, ldfrag(wt + 1536), acc[tt], 0, 0, 0);
            }
        }
        __syncthreads();
    }
#pragma unroll
    for (int t = 0; t < NTILES; t++) {
        float b = BP[t * 16 + m];
#pragma unroll
        for (int r = 0; r < 4; r++) {
            int grow = rowbase + quad * 4 + r;
            if (grow < n) Y[(size_t)grow * COLS + t * 16 + m] = acc[t][r] + b;
        }
    }
}

// ---------------------------------------------------------------------------
// prep
// ---------------------------------------------------------------------------
__global__ __launch_bounds__(256) void prep(
    const float* __restrict__ x, unsigned short* __restrict__ XB,
    const float* __restrict__ Wk1, const float* __restrict__ Wv1,
    const float* __restrict__ Wq1, const float* __restrict__ Wskip1,
    const float* __restrict__ bk1, const float* __restrict__ bv1,
    const float* __restrict__ bq1, const float* __restrict__ bskip1,
    const float* __restrict__ Wk2, const float* __restrict__ Wv2,
    const float* __restrict__ Wq2, const float* __restrict__ Wskip2,
    const float* __restrict__ bk2, const float* __restrict__ bv2,
    const float* __restrict__ bq2, const float* __restrict__ bskip2,
    unsigned short* __restrict__ WB1, float* __restrict__ BP1,
    unsigned short* __restrict__ WB2, float* __restrict__ BP2,
    const float* __restrict__ edge_W, const float* __restrict__ edge_b,
    const float* __restrict__ time_W, const float* __restrict__ time_b,
    const float* __restrict__ We1, const float* __restrict__ We2,
    float* __restrict__ TA1, float* __restrict__ TB1,
    float* __restrict__ TA2, float* __restrict__ TB2,
    int* __restrict__ cnt1, int* __restrict__ cnt2, int* __restrict__ done) {
    int tid = blockIdx.x * blockDim.x + threadIdx.x;
    int stride = gridDim.x * blockDim.x;
    for (int i = tid; i < N0 * 32; i += stride) {
        float4 v = *(const float4*)(x + (size_t)i * 4);
        ushort4 u;
        u.x = f2b(v.x); u.y = f2b(v.y); u.z = f2b(v.z); u.w = f2b(v.w);
        *(ushort4*)(XB + (size_t)i * 4) = u;
    }
    for (int i = tid; i < 512 * 128; i += stride) {
        int j = i & 7, l = (i >> 3) & 63, ks = (i >> 9) & 3, t = i >> 11;
        int row = t * 16 + (l & 15);
        int col = ks * 32 + ((l >> 4) & 3) * 8 + j;
        const float* w; int off;
        if (row < 128) { w = Wk1; off = 0; }
        else if (row < 256) { w = Wv1; off = 128; }
        else if (row < 384) { w = Wq1; off = 256; }
        else { w = Wskip1; off = 384; }
        WB1[i] = f2b(w[(size_t)(row - off) * 128 + col]);
    }
    for (int i = tid; i < 512; i += stride) {
        const float* b; int off;
        if (i < 128) { b = bk1; off = 0; }
        else if (i < 256) { b = bv1; off = 128; }
        else if (i < 384) { b = bq1; off = 256; }
        else { b = bskip1; off = 384; }
        BP1[i] = b[i - off];
    }
    for (int i = tid; i < 448 * 128; i += stride) {
        int j = i & 7, l = (i >> 3) & 63, ks = (i >> 9) & 3, t = i >> 11;
        int row = t * 16 + (l & 15);
        int col = ks * 32 + ((l >> 4) & 3) * 8 + j;
        const float* w; int off;
        if (row < 128) { w = Wk2; off = 0; }
        else if (row < 256) { w = Wv2; off = 128; }
        else if (row < 384) { w = Wq2; off = 256; }
        else { w = Wskip2; off = 384; }
        WB2[i] = f2b(w[(size_t)(row - off) * 128 + col]);
    }
    for (int i = tid; i < 448; i += stride) {
        const float* b; int off;
        if (i < 128) { b = bk2; off = 0; }
        else if (i < 256) { b = bv2; off = 128; }
        else if (i < 384) { b = bq2; off = 256; }
        else { b = bskip2; off = 384; }
        BP2[i] = b[i - off];
    }
    const int TBL = (NTYPE + NTS) * 128;
    for (int i = tid; i < TBL; i += stride) {
        if (i < NTYPE * 128) {
            int e = i >> 7, c = i & 127;
            float s1 = 0.f, s2 = 0.f;
#pragma unroll
            for (int j = 0; j < 10; j++) {
                float fj = edge_W[j * NTYPE + e] + edge_b[j];
                s1 += fj * We1[c * 20 + j];
                s2 += fj * We2[c * 20 + j];
            }
            TA1[i] = s1; TA2[i] = s2;
        } else {
            int u = i - NTYPE * 128;
            int ts = u >> 7, c = u & 127;
            float s1 = 0.f, s2 = 0.f;
#pragma unroll
            for (int j = 0; j < 10; j++) {
                float fj = time_W[j * NTS + ts] + time_b[j];
                s1 += fj * We1[c * 20 + 10 + j];
                s2 += fj * We2[c * 20 + 10 + j];
            }
            TB1[u] = s1; TB2[u] = s2;
        }
    }
    for (int i = tid; i < N1 + N2 + 2; i += stride) {
        if (i < N1) cnt1[i] = 0;
        else if (i < N1 + N2) cnt2[i - N1] = 0;
        else done[i - N1 - N2] = 0;
    }
}

// ---------------------------------------------------------------------------
// mega_l1: degree count FIRST (atomic drain overlaps GEMM), then KV1 GEMM,
// then QR1 GEMM.
// ---------------------------------------------------------------------------
__global__ __launch_bounds__(256) void mega_l1(
    const unsigned short* __restrict__ XB,
    const unsigned short* __restrict__ WB1, const float* __restrict__ BP1,
    unsigned short* __restrict__ KV1, float* __restrict__ QR1,
    const int* __restrict__ d1, const int* __restrict__ d2,
    int* __restrict__ cnt1, int* __restrict__ cnt2,
    int* __restrict__ rk1, int* __restrict__ rk2) {
    __shared__ __align__(16) unsigned short sbuf[SMEM_USHORTS];
    int b = blockIdx.x;
    if (b < CNTB) {
        int t = b * 256 + threadIdx.x;
        if (t < E1C) rk1[t] = atomicAdd(&cnt1[d1[t]], 1);
        else {
            t -= E1C;
            if (t < E2C) rk2[t] = atomicAdd(&cnt2[d2[t]], 1);
        }
    } else if (b < CNTB + KV1B) {
        dev_gemm_bf16out<16>(XB, WB1, BP1, KV1, N0, b - CNTB, sbuf);
    } else {
        dev_gemm_f32out<16>(XB, WB1 + 256 * 128, BP1 + 256, QR1, N1,
                            b - CNTB - KV1B, sbuf);
    }
}

__global__ __launch_bounds__(256) void gemm_l2(
    const unsigned short* __restrict__ H,
    const unsigned short* __restrict__ WB2, const float* __restrict__ BP2,
    unsigned short* __restrict__ KV2, float* __restrict__ QR2) {
    __shared__ __align__(16) unsigned short sbuf[SMEM_USHORTS];
    int b = blockIdx.x;
    if (b < KV2B) dev_gemm_bf16out<16>(H, WB2, BP2, KV2, N1, b, sbuf);
    else dev_gemm_f32out<12>(H, WB2 + 256 * 128, BP2 + 256, QR2, N2, b - KV2B, sbuf);
}

// ---------------------------------------------------------------------------
// csr_scan (no cursor re-zero needed — fill uses precomputed ranks)
// ---------------------------------------------------------------------------
__global__ __launch_bounds__(256) void csr_scan(
    int* __restrict__ cnt1, int* __restrict__ bs1, int* __restrict__ rp1,
    int* __restrict__ cnt2, int* __restrict__ bs2, int* __restrict__ rp2,
    int* __restrict__ done) {
    __shared__ int s[256];
    __shared__ int amlast;
    int b = blockIdx.x;
    int* cnt; int* bs; int* rp; int n, lb;
    if (b < NB1) { cnt = cnt1; bs = bs1; rp = rp1; n = N1; lb = b; }
    else { cnt = cnt2; bs = bs2; rp = rp2; n = N2; lb = b - NB1; }
    int t = lb * 256 + threadIdx.x;
    int v = (t < n) ? cnt[t] : 0;
    s[threadIdx.x] = v;
    __syncthreads();
    for (int off = 128; off; off >>= 1) {
        if (threadIdx.x < off) s[threadIdx.x] += s[threadIdx.x + off];
        __syncthreads();
    }
    if (threadIdx.x == 0) {
        atomicExch(&bs[lb], s[0]);
        __threadfence();
        int prev = atomicAdd(&done[0], 1);
        amlast = (prev == NB1 + NB2 - 1) ? 1 : 0;
    }
    __syncthreads();
    if (amlast) {
        int tt = threadIdx.x;
        int v1 = (tt < NB1) ? atomicAdd(&bs1[tt], 0) : 0;
        s[tt] = v1;
        __syncthreads();
        for (int off = 1; off < 256; off <<= 1) {
            int u = (tt >= off) ? s[tt - off] : 0;
            __syncthreads();
            s[tt] += u;
            __syncthreads();
        }
        if (tt < NB1) atomicExch(&bs1[tt], s[tt] - v1);
        __syncthreads();
        int v2 = (tt < NB2) ? atomicAdd(&bs2[tt], 0) : 0;
        s[tt] = v2;
        __syncthreads();
        for (int off = 1; off < 256; off <<= 1) {
            int u = (tt >= off) ? s[tt - off] : 0;
            __syncthreads();
            s[tt] += u;
            __syncthreads();
        }
        if (tt < NB2) atomicExch(&bs2[tt], s[tt] - v2);
        __threadfence();
        __syncthreads();
        if (tt == 0) atomicExch(&done[1], 1);
    }
    if (threadIdx.x == 0) {
        while (atomicAdd(&done[1], 0) == 0) __builtin_amdgcn_s_sleep(1);
    }
    __syncthreads();
    __threadfence();
    int base = atomicAdd(&bs[lb], 0);
    s[threadIdx.x] = v;
    __syncthreads();
    for (int off = 1; off < 256; off <<= 1) {
        int u = (threadIdx.x >= off) ? s[threadIdx.x - off] : 0;
        __syncthreads();
        s[threadIdx.x] += u;
        __syncthreads();
    }
    int incl = s[threadIdx.x];
    if (t < n) rp[t] = base + incl - v;
    if (t == n - 1) rp[n] = base + incl;
}

// ---------------------------------------------------------------------------
// fill_both: atomic-free scatter using precomputed ranks (max TLP)
// ---------------------------------------------------------------------------
__global__ __launch_bounds__(256) void fill_both(
    const int* __restrict__ d1, const int* __restrict__ s1,
    const int* __restrict__ et1, const int* __restrict__ ets1,
    const int* __restrict__ rp1, const int* __restrict__ rk1, uint2* __restrict__ ed1,
    const int* __restrict__ d2, const int* __restrict__ s2,
    const int* __restrict__ et2, const int* __restrict__ ets2,
    const int* __restrict__ rp2, const int* __restrict__ rk2, uint2* __restrict__ ed2) {
    int t = blockIdx.x * 256 + threadIdx.x;
    if (t < E1C) {
        int pos = rp1[d1[t]] + rk1[t];
        ed1[pos] = make_uint2((unsigned)s1[t],
                              (unsigned)(et1[t] | (ets1[t] << 16)));
    } else {
        t -= E1C;
        if (t < E2C) {
            int pos = rp2[d2[t]] + rk2[t];
            ed2[pos] = make_uint2((unsigned)s2[t],
                                  (unsigned)(et2[t] | (ets2[t] << 16)));
        }
    }
}

// ---------------------------------------------------------------------------
// Fused aggregation — 16 lanes per edge, 4 edge slots per wave.
// lane layout: eg = lane>>4 (edge slot 0..3), cg = lane&15, channels
// [8*cg, 8*cg+8). Head h = cg>>3 (64 channels = 8 lanes each).
// Per-head QK dot = red8 (3 DPP steps) within each 8-lane half-row.
// 2x memory-level parallelism and half the serial iterations vs the old
// 2-slot layout; e = TA+TB folded at load time. Depth-3 rotation pipeline.
// ---------------------------------------------------------------------------
static __device__ __forceinline__ void edge_accum(
    int beg, int end, int eg, int co, float4 qA, float4 qB,
    const uint2* __restrict__ ED, const float* __restrict__ TA,
    const float* __restrict__ TB, const unsigned short* __restrict__ KV,
    float4& accA, float4& accB, float& suma) {
    int p = beg + eg;
    if (p >= end) return;

    uint2 d0 = ED[p];
    int pA = p + 4;  bool mA = pA < end;
    uint2 d1 = ED[mA ? pA : beg];
    int pB = p + 8;  bool mB = pB < end;
    uint2 d2 = ED[mB ? pB : beg];

    float4 eA0, eB0, eA1, eB1, eA2, eB2;
    uint4 ku0, vu0, ku1, vu1, ku2, vu2;

#define LOADSET4(S, D) { \
    int t_ = (int)(D.y & 0xFFFF), ts_ = (int)(D.y >> 16); \
    const float* ta_ = TA + t_ * 128 + co; \
    const float* tb_ = TB + ts_ * 128 + co; \
    float4 a0_ = *(const float4*)ta_, a1_ = *(const float4*)(ta_ + 4); \
    float4 b0_ = *(const float4*)tb_, b1_ = *(const float4*)(tb_ + 4); \
    eA##S = make_float4(a0_.x + b0_.x, a0_.y + b0_.y, a0_.z + b0_.z, a0_.w + b0_.w); \
    eB##S = make_float4(a1_.x + b1_.x, a1_.y + b1_.y, a1_.z + b1_.z, a1_.w + b1_.w); \
    const unsigned short* kv_ = KV + (size_t)D.x * 256 + co; \
    ku##S = *(const uint4*)kv_; \
    vu##S = *(const uint4*)(kv_ + 128); }

    LOADSET4(0, d0)
    LOADSET4(1, d1)
    for (;;) {
        int pC = pB + 4; bool mC = pC < end;
        uint2 d3 = ED[mC ? pC : beg];
        LOADSET4(2, d2)
        {
            f32x2 k01 = b2f2(ku0.x), k23 = b2f2(ku0.y);
            f32x2 k45 = b2f2(ku0.z), k67 = b2f2(ku0.w);
            float pp = qA.x * (k01.x + eA0.x) + qA.y * (k01.y + eA0.y)
                     + qA.z * (k23.x + eA0.z) + qA.w * (k23.y + eA0.w)
                     + qB.x * (k45.x + eB0.x) + qB.y * (k45.y + eB0.y)
                     + qB.z * (k67.x + eB0.z) + qB.w * (k67.y + eB0.w);
            pp = red8(pp);
            float a = __expf(pp * 0.125f);
            f32x2 v01 = b2f2(vu0.x), v23 = b2f2(vu0.y);
            f32x2 v45 = b2f2(vu0.z), v67 = b2f2(vu0.w);
            accA.x += a * (v01.x + eA0.x); accA.y += a * (v01.y + eA0.y);
            accA.z += a * (v23.x + eA0.z); accA.w += a * (v23.y + eA0.w);
            accB.x += a * (v45.x + eB0.x); accB.y += a * (v45.y + eB0.y);
            accB.z += a * (v67.x + eB0.z); accB.w += a * (v67.y + eB0.w);
            suma += a;
        }
        if (!mA) break;
        eA0 = eA1; eB0 = eB1; ku0 = ku1; vu0 = vu1;
        eA1 = eA2; eB1 = eB2; ku1 = ku2; vu1 = vu2;
        d2 = d3;
        mA = mB; mB = mC; pB = pC;
    }
#undef LOADSET4
}

#define CMB2(x) { x += __shfl_xor(x, 16); x += __shfl_xor(x, 32); }

__global__ __launch_bounds__(256) void agg_layer1(
    const int* __restrict__ rowptr, const uint2* __restrict__ ED,
    const float* __restrict__ TA, const float* __restrict__ TB,
    const float* __restrict__ QR, const unsigned short* __restrict__ KV,
    const float* __restrict__ Wbeta,
    const float* __restrict__ ln_g, const float* __restrict__ ln_b,
    unsigned short* __restrict__ hout, int n) {
    int wid = (blockIdx.x * blockDim.x + threadIdx.x) >> 6;
    int lane = threadIdx.x & 63;
    if (wid >= n) return;
    int eg = lane >> 4, cg = lane & 15;
    int co = cg * 8;
    int beg = rowptr[wid], end = rowptr[wid + 1];
    const float* qp = QR + (size_t)wid * 256 + co;
    float4 qA = *(const float4*)qp, qB = *(const float4*)(qp + 4);
    float4 accA = make_float4(0.f, 0.f, 0.f, 0.f);
    float4 accB = make_float4(0.f, 0.f, 0.f, 0.f);
    float suma = 0.f;
    edge_accum(beg, end, eg, co, qA, qB, ED, TA, TB, KV, accA, accB, suma);
    CMB2(accA.x) CMB2(accA.y) CMB2(accA.z) CMB2(accA.w)
    CMB2(accB.x) CMB2(accB.y) CMB2(accB.z) CMB2(accB.w)
    CMB2(suma)
    float inv_s = 1.f / (suma + 1e-16f);
    float o0 = accA.x * inv_s, o1 = accA.y * inv_s;
    float o2 = accA.z * inv_s, o3 = accA.w * inv_s;
    float o4 = accB.x * inv_s, o5 = accB.y * inv_s;
    float o6 = accB.z * inv_s, o7 = accB.w * inv_s;
    const float* rp_ = QR + (size_t)wid * 256 + 128 + co;
    float4 rA = *(const float4*)rp_, rB = *(const float4*)(rp_ + 4);
    float4 woA = *(const float4*)(Wbeta + co);
    float4 woB = *(const float4*)(Wbeta + co + 4);
    float4 wrA = *(const float4*)(Wbeta + 128 + co);
    float4 wrB = *(const float4*)(Wbeta + 128 + co + 4);
    float4 wdA = *(const float4*)(Wbeta + 256 + co);
    float4 wdB = *(const float4*)(Wbeta + 256 + co + 4);
    float pb = woA.x * o0 + wrA.x * rA.x + wdA.x * (o0 - rA.x)
             + woA.y * o1 + wrA.y * rA.y + wdA.y * (o1 - rA.y)
             + woA.z * o2 + wrA.z * rA.z + wdA.z * (o2 - rA.z)
             + woA.w * o3 + wrA.w * rA.w + wdA.w * (o3 - rA.w)
             + woB.x * o4 + wrB.x * rB.x + wdB.x * (o4 - rB.x)
             + woB.y * o5 + wrB.y * rB.y + wdB.y * (o5 - rB.y)
             + woB.z * o6 + wrB.z * rB.z + wdB.z * (o6 - rB.z)
             + woB.w * o7 + wrB.w * rB.w + wdB.w * (o7 - rB.w);
    pb = red16(pb);
    float beta = 1.f / (1.f + __expf(-pb));
    float g0 = beta * rA.x + (1.f - beta) * o0;
    float g1 = beta * rA.y + (1.f - beta) * o1;
    float g2 = beta * rA.z + (1.f - beta) * o2;
    float g3 = beta * rA.w + (1.f - beta) * o3;
    float g4 = beta * rB.x + (1.f - beta) * o4;
    float g5 = beta * rB.y + (1.f - beta) * o5;
    float g6 = beta * rB.z + (1.f - beta) * o6;
    float g7 = beta * rB.w + (1.f - beta) * o7;
    float sm = g0 + g1 + g2 + g3 + g4 + g5 + g6 + g7;
    float sq = g0 * g0 + g1 * g1 + g2 * g2 + g3 * g3
             + g4 * g4 + g5 * g5 + g6 * g6 + g7 * g7;
    sm = red16(sm);
    sq = red16(sq);
    float mu = sm * (1.f / 128.f);
    float var = sq * (1.f / 128.f) - mu * mu;
    float inv = rsqrtf(var + 1e-5f);
    float4 lgA = *(const float4*)(ln_g + co);
    float4 lgB = *(const float4*)(ln_g + co + 4);
    float4 lbA = *(const float4*)(ln_b + co);
    float4 lbB = *(const float4*)(ln_b + co + 4);
    float y0 = (g0 - mu) * inv * lgA.x + lbA.x;
    float y1 = (g1 - mu) * inv * lgA.y + lbA.y;
    float y2 = (g2 - mu) * inv * lgA.z + lbA.z;
    float y3 = (g3 - mu) * inv * lgA.w + lbA.w;
    float y4 = (g4 - mu) * inv * lgB.x + lbB.x;
    float y5 = (g5 - mu) * inv * lgB.y + lbB.y;
    float y6 = (g6 - mu) * inv * lgB.z + lbB.z;
    float y7 = (g7 - mu) * inv * lgB.w + lbB.w;
    const float ISQ2 = 0.70710678118654752f;
    y0 = 0.5f * y0 * (1.f + erff(y0 * ISQ2));
    y1 = 0.5f * y1 * (1.f + erff(y1 * ISQ2));
    y2 = 0.5f * y2 * (1.f + erff(y2 * ISQ2));
    y3 = 0.5f * y3 * (1.f + erff(y3 * ISQ2));
    y4 = 0.5f * y4 * (1.f + erff(y4 * ISQ2));
    y5 = 0.5f * y5 * (1.f + erff(y5 * ISQ2));
    y6 = 0.5f * y6 * (1.f + erff(y6 * ISQ2));
    y7 = 0.5f * y7 * (1.f + erff(y7 * ISQ2));
    if (eg == 0) {
        unsigned u0 = (unsigned)f2b(y0) | ((unsigned)f2b(y1) << 16);
        unsigned u1 = (unsigned)f2b(y2) | ((unsigned)f2b(y3) << 16);
        unsigned u2 = (unsigned)f2b(y4) | ((unsigned)f2b(y5) << 16);
        unsigned u3 = (unsigned)f2b(y6) | ((unsigned)f2b(y7) << 16);
        *(uint4*)(hout + (size_t)wid * 128 + co) = make_uint4(u0, u1, u2, u3);
    }
}

__global__ __launch_bounds__(256) void agg_layer2(
    const int* __restrict__ rowptr, const uint2* __restrict__ ED,
    const float* __restrict__ TA, const float* __restrict__ TB,
    const float* __restrict__ QR, const unsigned short* __restrict__ KV,
    const float* __restrict__ Wbeta,
    float* __restrict__ o, int n) {
    int wid = (blockIdx.x * blockDim.x + threadIdx.x) >> 6;
    int lane = threadIdx.x & 63;
    if (wid >= n) return;
    int eg = lane >> 4, cg = lane & 15;
    int co = cg * 8;
    int beg = rowptr[wid], end = rowptr[wid + 1];
    const float* qp = QR + (size_t)wid * 192 + co;
    float4 qA = *(const float4*)qp, qB = *(const float4*)(qp + 4);
    float4 accA = make_float4(0.f, 0.f, 0.f, 0.f);
    float4 accB = make_float4(0.f, 0.f, 0.f, 0.f);
    float suma = 0.f;
    edge_accum(beg, end, eg, co, qA, qB, ED, TA, TB, KV, accA, accB, suma);
    CMB2(accA.x) CMB2(accA.y) CMB2(accA.z) CMB2(accA.w)
    CMB2(accB.x) CMB2(accB.y) CMB2(accB.z) CMB2(accB.w)
    CMB2(suma)
    float inv_s = 1.f / (suma + 1e-16f);
    float o0 = accA.x * inv_s, o1 = accA.y * inv_s;
    float o2 = accA.z * inv_s, o3 = accA.w * inv_s;
    float o4 = accB.x * inv_s, o5 = accB.y * inv_s;
    float o6 = accB.z * inv_s, o7 = accB.w * inv_s;
    // mean over heads: channel c (head0, lanes cg<8) pairs with c+64 (lanes cg+8)
    o0 = 0.5f * (o0 + __shfl_xor(o0, 8));
    o1 = 0.5f * (o1 + __shfl_xor(o1, 8));
    o2 = 0.5f * (o2 + __shfl_xor(o2, 8));
    o3 = 0.5f * (o3 + __shfl_xor(o3, 8));
    o4 = 0.5f * (o4 + __shfl_xor(o4, 8));
    o5 = 0.5f * (o5 + __shfl_xor(o5, 8));
    o6 = 0.5f * (o6 + __shfl_xor(o6, 8));
    o7 = 0.5f * (o7 + __shfl_xor(o7, 8));
    int oc = (cg & 7) * 8;   // output channels [oc, oc+8)
    const float* rp_ = QR + (size_t)wid * 192 + 128 + oc;
    float4 rA = *(const float4*)rp_, rB = *(const float4*)(rp_ + 4);
    float4 woA = *(const float4*)(Wbeta + oc);
    float4 woB = *(const float4*)(Wbeta + oc + 4);
    float4 wrA = *(const float4*)(Wbeta + 64 + oc);
    float4 wrB = *(const float4*)(Wbeta + 64 + oc + 4);
    float4 wdA = *(const float4*)(Wbeta + 128 + oc);
    float4 wdB = *(const float4*)(Wbeta + 128 + oc + 4);
    float pb = woA.x * o0 + wrA.x * rA.x + wdA.x * (o0 - rA.x)
             + woA.y * o1 + wrA.y * rA.y + wdA.y * (o1 - rA.y)
             + woA.z * o2 + wrA.z * rA.z + wdA.z * (o2 - rA.z)
             + woA.w * o3 + wrA.w * rA.w + wdA.w * (o3 - rA.w)
             + woB.x * o4 + wrB.x * rB.x + wdB.x * (o4 - rB.x)
             + woB.y * o5 + wrB.y * rB.y + wdB.y * (o5 - rB.y)
             + woB.z * o6 + wrB.z * rB.z + wdB.z * (o6 - rB.z)
             + woB.w * o7 + wrB.w * rB.w + wdB.w * (o7 - rB.w);
    pb = red8(pb);   // both 8-lane halves independently hold the full 64-dot
    float beta = 1.f / (1.f + __expf(-pb));
    float v0 = beta * rA.x + (1.f - beta) * o0;
    float v1 = beta * rA.y + (1.f - beta) * o1;
    float v2 = beta * rA.z + (1.f - beta) * o2;
    float v3 = beta * rA.w + (1.f - beta) * o3;
    float v4 = beta * rB.x + (1.f - beta) * o4;
    float v5 = beta * rB.y + (1.f - beta) * o5;
    float v6 = beta * rB.z + (1.f - beta) * o6;
    float v7 = beta * rB.w + (1.f - beta) * o7;
    float mm = fmaxf(fmaxf(fmaxf(v0, v1), fmaxf(v2, v3)),
                     fmaxf(fmaxf(v4, v5), fmaxf(v6, v7)));
    mm = red8max(mm);
    float se = __expf(v0 - mm) + __expf(v1 - mm) + __expf(v2 - mm) + __expf(v3 - mm)
             + __expf(v4 - mm) + __expf(v5 - mm) + __expf(v6 - mm) + __expf(v7 - mm);
    se = red8(se);
    float lse = mm + logf(se);
    if (eg == 0 && cg < 8) {
        float* op = o + (size_t)wid * 64 + oc;
        *(float4*)op = make_float4(v0 - lse, v1 - lse, v2 - lse, v3 - lse);
        *(float4*)(op + 4) = make_float4(v4 - lse, v5 - lse, v6 - lse, v7 - lse);
    }
}

extern "C" void kernel_launch(void* const* d_in, const int* in_sizes, int n_in,
                              void* d_out, int out_size, void* d_ws, size_t ws_size,
                              hipStream_t stream) {
    const float* x        = (const float*)d_in[0];
    const int*   ei1_src  = (const int*)d_in[1];
    const int*   ei1_dst  = (const int*)d_in[2];
    const int*   et1      = (const int*)d_in[3];
    const int*   ets1     = (const int*)d_in[4];
    const int*   ei2_src  = (const int*)d_in[5];
    const int*   ei2_dst  = (const int*)d_in[6];
    const int*   et2      = (const int*)d_in[7];
    const int*   ets2     = (const int*)d_in[8];
    const float* edge_W   = (const float*)d_in[9];
    const float* edge_b   = (const float*)d_in[10];
    const float* time_W   = (const float*)d_in[11];
    const float* time_b   = (const float*)d_in[12];
    const float* Wq1      = (const float*)d_in[13];
    const float* bq1      = (const float*)d_in[14];
    const float* Wk1      = (const float*)d_in[15];
    const float* bk1      = (const float*)d_in[16];
    const float* Wv1      = (const float*)d_in[17];
    const float* bv1      = (const float*)d_in[18];
    const float* We1      = (const float*)d_in[19];
    const float* Wskip1   = (const float*)d_in[20];
    const float* bskip1   = (const float*)d_in[21];
    const float* Wbeta1   = (const float*)d_in[22];
    const float* ln_g     = (const float*)d_in[23];
    const float* ln_b     = (const float*)d_in[24];
    const float* Wq2      = (const float*)d_in[25];
    const float* bq2      = (const float*)d_in[26];
    const float* Wk2      = (const float*)d_in[27];
    const float* bk2      = (const float*)d_in[28];
    const float* Wv2      = (const float*)d_in[29];
    const float* bv2      = (const float*)d_in[30];
    const float* We2      = (const float*)d_in[31];
    const float* Wskip2   = (const float*)d_in[32];
    const float* bskip2   = (const float*)d_in[33];
    const float* Wbeta2   = (const float*)d_in[34];

    float* ws = (float*)d_ws;
    unsigned short* xb  = (unsigned short*)(ws + OFF_XB);
    float* qr1          = ws + OFF_QR1;
    unsigned short* kv1 = (unsigned short*)(ws + OFF_KV1);
    unsigned short* h   = (unsigned short*)(ws + OFF_H);
    float* qr2          = ws + OFF_QR2;
    unsigned short* kv2 = (unsigned short*)(ws + OFF_KV2);
    unsigned short* wb1 = (unsigned short*)(ws + OFF_WB1);
    float* bp1          = ws + OFF_BP1;
    unsigned short* wb2 = (unsigned short*)(ws + OFF_WB2);
    float* bp2          = ws + OFF_BP2;
    float* ta1          = ws + OFF_TA1;
    float* tb1          = ws + OFF_TB1;
    float* ta2          = ws + OFF_TA2;
    float* tb2          = ws + OFF_TB2;
    int*   rp1          = (int*)(ws + OFF_RP1);
    int*   cur1         = (int*)(ws + OFF_CUR1);
    uint2* ed1          = (uint2*)(ws + OFF_ED1);
    int*   bs1          = (int*)(ws + OFF_BS1);
    int*   rp2          = (int*)(ws + OFF_RP2);
    int*   cur2         = (int*)(ws + OFF_CUR2);
    uint2* ed2          = (uint2*)(ws + OFF_ED2);
    int*   bs2          = (int*)(ws + OFF_BS2);
    int*   done         = (int*)(ws + OFF_DONE);
    int*   rk1          = (int*)(ws + OFF_RK1);
    int*   rk2          = (int*)(ws + OFF_RK2);

    prep<<<2048, 256, 0, stream>>>(
        x, xb,
        Wk1, Wv1, Wq1, Wskip1, bk1, bv1, bq1, bskip1,
        Wk2, Wv2, Wq2, Wskip2, bk2, bv2, bq2, bskip2,
        wb1, bp1, wb2, bp2,
        edge_W, edge_b, time_W, time_b, We1, We2,
        ta1, tb1, ta2, tb2, cur1, cur2, done);
    mega_l1<<<KV1B + QR1B + CNTB, 256, 0, stream>>>(
        xb, wb1, bp1, kv1, qr1, ei1_dst, ei2_dst, cur1, cur2, rk1, rk2);
    csr_scan<<<NB1 + NB2, 256, 0, stream>>>(cur1, bs1, rp1, cur2, bs2, rp2, done);
    fill_both<<<FILLB, 256, 0, stream>>>(
        ei1_dst, ei1_src, et1, ets1, rp1, rk1, ed1,
        ei2_dst, ei2_src, et2, ets2, rp2, rk2, ed2);
    agg_layer1<<<(N1 + 3) / 4, 256, 0, stream>>>(rp1, ed1,
        ta1, tb1, qr1, kv1, Wbeta1, ln_g, ln_b, h, N1);
    gemm_l2<<<KV2B + QR2B, 256, 0, stream>>>(h, wb2, bp2, kv2, qr2);
    agg_layer2<<<(N2 + 3) / 4, 256, 0, stream>>>(rp2, ed2,
        ta2, tb2, qr2, kv2, Wbeta2, (float*)d_out, N2);
}

// Round 7
// 351.827 us; speedup vs baseline: 1.0621x; 1.0571x over previous
//
#include <hip/hip_runtime.h>
#include <math.h>

// Problem constants
#define N0 80000
#define N1 40000
#define N2 20000
#define E1C 500000
#define E2C 250000
#define NTYPE 23
#define NTS 1158

// derived grid constants
#define NB1 157
#define NB2 79
#define KV1B 1250
#define QR1B 625
#define CNTB 2930
#define KV2B 625
#define QR2B 313
#define FILLB 2930

// ---------------- Workspace layout (float offsets) ----------------
#define OFF_XB    0u
#define OFF_QR1   5120000u
#define OFF_KV1   15360000u
#define OFF_H     25600000u
#define OFF_QR2   28160000u
#define OFF_KV2   32000000u
#define OFF_WB1   37120000u
#define OFF_BP1   37160000u
#define OFF_WB2   37170000u
#define OFF_BP2   37200000u
#define OFF_TA1   37210000u
#define OFF_TB1   37213000u
#define OFF_TA2   37370000u
#define OFF_TB2   37373000u
#define OFF_RP1   37530000u
#define OFF_CUR1  37580000u
#define OFF_ED1   37630000u
#define OFF_BS1   38640000u
#define OFF_RP2   38650000u
#define OFF_CUR2  38680000u
#define OFF_ED2   38710000u
#define OFF_BS2   39220000u
#define OFF_DONE  39230000u    // 2 ints
#define OFF_RK1   39240000u    // E1 ints (edge rank within dst)
#define OFF_RK2   39740000u    // E2 ints -> ends 39,990,000 (~160 MB)

typedef __bf16 bf16x8 __attribute__((ext_vector_type(8)));
typedef float f32x4 __attribute__((ext_vector_type(4)));

static __device__ __forceinline__ float b2f(unsigned short u) {
    union { unsigned int i; float f; } c;
    c.i = ((unsigned int)u) << 16;
    return c.f;
}
static __device__ __forceinline__ unsigned short f2b(float f) {
    unsigned int u = __float_as_uint(f);
    unsigned int r = (u + 0x7fffu + ((u >> 16) & 1u)) >> 16;
    return (unsigned short)r;
}
static __device__ __forceinline__ bf16x8 ldfrag(const unsigned short* p) {
    return *reinterpret_cast<const bf16x8*>(p);
}

// async global->LDS copy, 16B per lane. LDS dest is wave-uniform base
// (HW adds lane*16); global src is per-lane.
static __device__ __forceinline__ void stage16(const void* g, void* l) {
    __builtin_amdgcn_global_load_lds(
        (const __attribute__((address_space(1))) unsigned int*)g,
        (__attribute__((address_space(3))) unsigned int*)l,
        16, 0, 0);
}

// DPP 16-lane reductions
template <int CTRL>
static __device__ __forceinline__ float dpp_addstep(float v) {
    int x = __builtin_amdgcn_mov_dpp(__float_as_int(v), CTRL, 0xF, 0xF, true);
    return v + __int_as_float(x);
}
static __device__ __forceinline__ float red16(float v) {
    v = dpp_addstep<0xB1>(v);
    v = dpp_addstep<0x4E>(v);
    v = dpp_addstep<0x141>(v);
    v = dpp_addstep<0x140>(v);
    return v;
}
template <int CTRL>
static __device__ __forceinline__ float dpp_maxstep(float v) {
    int x = __builtin_amdgcn_mov_dpp(__float_as_int(v), CTRL, 0xF, 0xF, true);
    return fmaxf(v, __int_as_float(x));
}
static __device__ __forceinline__ float red16max(float v) {
    v = dpp_maxstep<0xB1>(v);
    v = dpp_maxstep<0x4E>(v);
    v = dpp_maxstep<0x141>(v);
    v = dpp_maxstep<0x140>(v);
    return v;
}

// ---------------------------------------------------------------------------
// Device GEMM bodies (MFMA 16x16x32 bf16), fragment-linear B.
// B panel staged block-cooperatively into LDS in 4-tile (16 KB) chunks,
// single-buffered. LDS total 17408 B -> 8 blocks/CU (thread cap) vs 5 at
// 32 KB: more co-resident blocks to overlap the per-chunk barrier drains.
// ---------------------------------------------------------------------------
#define LDSS 136
#define SMEM_USHORTS 8704   // 17408 B: 16 KB staging chunk + epilogue scratch

template <int NTILES>
static __device__ __forceinline__ void dev_gemm_bf16out(
    const unsigned short* __restrict__ XB, const unsigned short* __restrict__ WB,
    const float* __restrict__ BP, unsigned short* __restrict__ Y, int n, int blk,
    unsigned short* sb) {
    constexpr int COLS = NTILES * 16;
    constexpr int HALF = NTILES / 2;
    constexpr int HCOLS = HALF * 16;
    constexpr int NCHUNK = (NTILES + 3) / 4;
    int wave = threadIdx.x >> 6, lane = threadIdx.x & 63;
    int m = lane & 15, quad = lane >> 4;
    int rowbase = blk * 64 + wave * 16;
    int arow = rowbase + m; if (arow >= n) arow = n - 1;
    unsigned short* swave = sb + wave * 16 * LDSS;
    const unsigned short* xrow = XB + (size_t)arow * 128 + quad * 8;
    bf16x8 a0 = ldfrag(xrow), a1 = ldfrag(xrow + 32);
    bf16x8 a2 = ldfrag(xrow + 64), a3 = ldfrag(xrow + 96);
    f32x4 acc[NTILES];
#pragma unroll
    for (int t = 0; t < NTILES; t++) acc[t] = (f32x4){0.f, 0.f, 0.f, 0.f};
    const char* gstage = (const char*)WB + wave * 1024 + lane * 16;
    char* lstage = (char*)sb + wave * 1024;
#pragma unroll
    for (int c = 0; c < NCHUNK; c++) {
#pragma unroll
        for (int i = 0; i < 4; i++)
            if (c * 4 + i < NTILES)
                stage16(gstage + (size_t)(c * 4 + i) * 4096, lstage + i * 4096);
        __syncthreads();
#pragma unroll
        for (int t = 0; t < 4; t++) {
            int tt = c * 4 + t;
            if (tt < NTILES) {
                const unsigned short* wt = sb + t * 2048 + lane * 8;
                acc[tt] = __builtin_amdgcn_mfma_f32_16x16x32_bf16(a0, ldfrag(wt), acc[tt], 0, 0, 0);
                acc[tt] = __builtin_amdgcn_mfma_f32_16x16x32_bf16(a1, ldfrag(wt + 512), acc[tt], 0, 0, 0);
                acc[tt] = __builtin_amdgcn_mfma_f32_16x16x32_bf16(a2, ldfrag(wt + 1024), acc[tt], 0, 0, 0);
                acc[tt] = __builtin_amdgcn_mfma_f32_16x16x32_bf16(a3, ldfrag(wt + 1536), acc[tt], 0, 0, 0);
            }
        }
        __syncthreads();
    }
    int tswz_bit = (quad >> 1) & 1;
#pragma unroll
    for (int half = 0; half < 2; half++) {
#pragma unroll
        for (int t = 0; t < HALF; t++) {
            int tt = half * HALF + t;
            int tsw = t ^ tswz_bit;
            float b = BP[tt * 16 + m];
#pragma unroll
            for (int r = 0; r < 4; r++)
                swave[(quad * 4 + r) * LDSS + tsw * 16 + m] = f2b(acc[tt][r] + b);
        }
#pragma unroll
        for (int i = 0; i < 4; i++) {
            int idx = i * 64 + lane;
            int r = idx / (HCOLS / 8), g = idx % (HCOLS / 8);
            int gs = g ^ (((r >> 3) & 1) << 1);
            int grow = rowbase + r;
            if (grow < n) {
                uint4 v = *(const uint4*)&swave[r * LDSS + gs * 8];
                *(uint4*)(Y + (size_t)grow * COLS + half * HCOLS + g * 8) = v;
            }
        }
    }
}

template <int NTILES>
static __device__ __forceinline__ void dev_gemm_f32out(
    const unsigned short* __restrict__ XB, const unsigned short* __restrict__ WB,
    const float* __restrict__ BP, float* __restrict__ Y, int n, int blk,
    unsigned short* sb) {
    constexpr int COLS = NTILES * 16;
    constexpr int NCHUNK = (NTILES + 3) / 4;
    int wave = threadIdx.x >> 6, lane = threadIdx.x & 63;
    int m = lane & 15, quad = lane >> 4;
    int rowbase = blk * 64 + wave * 16;
    int arow = rowbase + m; if (arow >= n) arow = n - 1;
    const unsigned short* xrow = XB + (size_t)arow * 128 + quad * 8;
    bf16x8 a0 = ldfrag(xrow), a1 = ldfrag(xrow + 32);
    bf16x8 a2 = ldfrag(xrow + 64), a3 = ldfrag(xrow + 96);
    f32x4 acc[NTILES];
#pragma unroll
    for (int t = 0; t < NTILES; t++) acc[t] = (f32x4){0.f, 0.f, 0.f, 0.f};
    const char* gstage = (const char*)WB + wave * 1024 + lane * 16;
    char* lstage = (char*)sb + wave * 1024;
#pragma unroll
    for (int c = 0; c < NCHUNK; c++) {
#pragma unroll
        for (int i = 0; i < 4; i++)
            if (c * 4 + i < NTILES)
                stage16(gstage + (size_t)(c * 4 + i) * 4096, lstage + i * 4096);
        __syncthreads();
#pragma unroll
        for (int t = 0; t < 4; t++) {
            int tt = c * 4 + t;
            if (tt < NTILES) {
                const unsigned short* wt = sb + t * 2048 + lane * 8;
                acc[tt] = __builtin_amdgcn_mfma_f32_16x16x32_bf16(a0, ldfrag(wt), acc[tt], 0, 0, 0);
                acc[tt] = __builtin_amdgcn_mfma_f32_16x16x32_bf16(a1, ldfrag(wt + 512), acc[tt], 0, 0, 0);
                acc[tt] = __builtin_amdgcn_mfma_f32_16x16x32_bf16(a2, ldfrag(wt + 1024), acc[tt], 0, 0, 0);
                acc[tt] = __builtin_amdgcn_mfma_f32_16x16x32_bf16(a3, ldfrag(wt + 1536), acc[tt], 0, 0, 0);
            }
        }
        __syncthreads();
    }
#pragma unroll
    for (int t = 0; t < NTILES; t++) {
        float b = BP[t * 16 + m];
#pragma unroll
        for (int r = 0; r < 4; r++) {
            int grow = rowbase + quad * 4 + r;
            if (grow < n) Y[(size_t)grow * COLS + t * 16 + m] = acc[t][r] + b;
        }
    }
}

// ---------------------------------------------------------------------------
// prep
// ---------------------------------------------------------------------------
__global__ __launch_bounds__(256) void prep(
    const float* __restrict__ x, unsigned short* __restrict__ XB,
    const float* __restrict__ Wk1, const float* __restrict__ Wv1,
    const float* __restrict__ Wq1, const float* __restrict__ Wskip1,
    const float* __restrict__ bk1, const float* __restrict__ bv1,
    const float* __restrict__ bq1, const float* __restrict__ bskip1,
    const float* __restrict__ Wk2, const float* __restrict__ Wv2,
    const float* __restrict__ Wq2, const float* __restrict__ Wskip2,
    const float* __restrict__ bk2, const float* __restrict__ bv2,
    const float* __restrict__ bq2, const float* __restrict__ bskip2,
    unsigned short* __restrict__ WB1, float* __restrict__ BP1,
    unsigned short* __restrict__ WB2, float* __restrict__ BP2,
    const float* __restrict__ edge_W, const float* __restrict__ edge_b,
    const float* __restrict__ time_W, const float* __restrict__ time_b,
    const float* __restrict__ We1, const float* __restrict__ We2,
    float* __restrict__ TA1, float* __restrict__ TB1,
    float* __restrict__ TA2, float* __restrict__ TB2,
    int* __restrict__ cnt1, int* __restrict__ cnt2, int* __restrict__ done) {
    int tid = blockIdx.x * blockDim.x + threadIdx.x;
    int stride = gridDim.x * blockDim.x;
    for (int i = tid; i < N0 * 32; i += stride) {
        float4 v = *(const float4*)(x + (size_t)i * 4);
        ushort4 u;
        u.x = f2b(v.x); u.y = f2b(v.y); u.z = f2b(v.z); u.w = f2b(v.w);
        *(ushort4*)(XB + (size_t)i * 4) = u;
    }
    for (int i = tid; i < 512 * 128; i += stride) {
        int j = i & 7, l = (i >> 3) & 63, ks = (i >> 9) & 3, t = i >> 11;
        int row = t * 16 + (l & 15);
        int col = ks * 32 + ((l >> 4) & 3) * 8 + j;
        const float* w; int off;
        if (row < 128) { w = Wk1; off = 0; }
        else if (row < 256) { w = Wv1; off = 128; }
        else if (row < 384) { w = Wq1; off = 256; }
        else { w = Wskip1; off = 384; }
        WB1[i] = f2b(w[(size_t)(row - off) * 128 + col]);
    }
    for (int i = tid; i < 512; i += stride) {
        const float* b; int off;
        if (i < 128) { b = bk1; off = 0; }
        else if (i < 256) { b = bv1; off = 128; }
        else if (i < 384) { b = bq1; off = 256; }
        else { b = bskip1; off = 384; }
        BP1[i] = b[i - off];
    }
    for (int i = tid; i < 448 * 128; i += stride) {
        int j = i & 7, l = (i >> 3) & 63, ks = (i >> 9) & 3, t = i >> 11;
        int row = t * 16 + (l & 15);
        int col = ks * 32 + ((l >> 4) & 3) * 8 + j;
        const float* w; int off;
        if (row < 128) { w = Wk2; off = 0; }
        else if (row < 256) { w = Wv2; off = 128; }
        else if (row < 384) { w = Wq2; off = 256; }
        else { w = Wskip2; off = 384; }
        WB2[i] = f2b(w[(size_t)(row - off) * 128 + col]);
    }
    for (int i = tid; i < 448; i += stride) {
        const float* b; int off;
        if (i < 128) { b = bk2; off = 0; }
        else if (i < 256) { b = bv2; off = 128; }
        else if (i < 384) { b = bq2; off = 256; }
        else { b = bskip2; off = 384; }
        BP2[i] = b[i - off];
    }
    const int TBL = (NTYPE + NTS) * 128;
    for (int i = tid; i < TBL; i += stride) {
        if (i < NTYPE * 128) {
            int e = i >> 7, c = i & 127;
            float s1 = 0.f, s2 = 0.f;
#pragma unroll
            for (int j = 0; j < 10; j++) {
                float fj = edge_W[j * NTYPE + e] + edge_b[j];
                s1 += fj * We1[c * 20 + j];
                s2 += fj * We2[c * 20 + j];
            }
            TA1[i] = s1; TA2[i] = s2;
        } else {
            int u = i - NTYPE * 128;
            int ts = u >> 7, c = u & 127;
            float s1 = 0.f, s2 = 0.f;
#pragma unroll
            for (int j = 0; j < 10; j++) {
                float fj = time_W[j * NTS + ts] + time_b[j];
                s1 += fj * We1[c * 20 + 10 + j];
                s2 += fj * We2[c * 20 + 10 + j];
            }
            TB1[u] = s1; TB2[u] = s2;
        }
    }
    for (int i = tid; i < N1 + N2 + 2; i += stride) {
        if (i < N1) cnt1[i] = 0;
        else if (i < N1 + N2) cnt2[i - N1] = 0;
        else done[i - N1 - N2] = 0;
    }
}

// ---------------------------------------------------------------------------
// mega_l1: degree count FIRST (atomic drain overlaps GEMM), then KV1 GEMM,
// then QR1 GEMM.
// ---------------------------------------------------------------------------
__global__ __launch_bounds__(256) void mega_l1(
    const unsigned short* __restrict__ XB,
    const unsigned short* __restrict__ WB1, const float* __restrict__ BP1,
    unsigned short* __restrict__ KV1, float* __restrict__ QR1,
    const int* __restrict__ d1, const int* __restrict__ d2,
    int* __restrict__ cnt1, int* __restrict__ cnt2,
    int* __restrict__ rk1, int* __restrict__ rk2) {
    __shared__ __align__(16) unsigned short sbuf[SMEM_USHORTS];
    int b = blockIdx.x;
    if (b < CNTB) {
        int t = b * 256 + threadIdx.x;
        if (t < E1C) rk1[t] = atomicAdd(&cnt1[d1[t]], 1);
        else {
            t -= E1C;
            if (t < E2C) rk2[t] = atomicAdd(&cnt2[d2[t]], 1);
        }
    } else if (b < CNTB + KV1B) {
        dev_gemm_bf16out<16>(XB, WB1, BP1, KV1, N0, b - CNTB, sbuf);
    } else {
        dev_gemm_f32out<16>(XB, WB1 + 256 * 128, BP1 + 256, QR1, N1,
                            b - CNTB - KV1B, sbuf);
    }
}

__global__ __launch_bounds__(256) void gemm_l2(
    const unsigned short* __restrict__ H,
    const unsigned short* __restrict__ WB2, const float* __restrict__ BP2,
    unsigned short* __restrict__ KV2, float* __restrict__ QR2) {
    __shared__ __align__(16) unsigned short sbuf[SMEM_USHORTS];
    int b = blockIdx.x;
    if (b < KV2B) dev_gemm_bf16out<16>(H, WB2, BP2, KV2, N1, b, sbuf);
    else dev_gemm_f32out<12>(H, WB2 + 256 * 128, BP2 + 256, QR2, N2, b - KV2B, sbuf);
}

// ---------------------------------------------------------------------------
// csr_scan (no cursor re-zero needed — fill uses precomputed ranks)
// ---------------------------------------------------------------------------
__global__ __launch_bounds__(256) void csr_scan(
    int* __restrict__ cnt1, int* __restrict__ bs1, int* __restrict__ rp1,
    int* __restrict__ cnt2, int* __restrict__ bs2, int* __restrict__ rp2,
    int* __restrict__ done) {
    __shared__ int s[256];
    __shared__ int amlast;
    int b = blockIdx.x;
    int* cnt; int* bs; int* rp; int n, lb;
    if (b < NB1) { cnt = cnt1; bs = bs1; rp = rp1; n = N1; lb = b; }
    else { cnt = cnt2; bs = bs2; rp = rp2; n = N2; lb = b - NB1; }
    int t = lb * 256 + threadIdx.x;
    int v = (t < n) ? cnt[t] : 0;
    s[threadIdx.x] = v;
    __syncthreads();
    for (int off = 128; off; off >>= 1) {
        if (threadIdx.x < off) s[threadIdx.x] += s[threadIdx.x + off];
        __syncthreads();
    }
    if (threadIdx.x == 0) {
        atomicExch(&bs[lb], s[0]);
        __threadfence();
        int prev = atomicAdd(&done[0], 1);
        amlast = (prev == NB1 + NB2 - 1) ? 1 : 0;
    }
    __syncthreads();
    if (amlast) {
        int tt = threadIdx.x;
        int v1 = (tt < NB1) ? atomicAdd(&bs1[tt], 0) : 0;
        s[tt] = v1;
        __syncthreads();
        for (int off = 1; off < 256; off <<= 1) {
            int u = (tt >= off) ? s[tt - off] : 0;
            __syncthreads();
            s[tt] += u;
            __syncthreads();
        }
        if (tt < NB1) atomicExch(&bs1[tt], s[tt] - v1);
        __syncthreads();
        int v2 = (tt < NB2) ? atomicAdd(&bs2[tt], 0) : 0;
        s[tt] = v2;
        __syncthreads();
        for (int off = 1; off < 256; off <<= 1) {
            int u = (tt >= off) ? s[tt - off] : 0;
            __syncthreads();
            s[tt] += u;
            __syncthreads();
        }
        if (tt < NB2) atomicExch(&bs2[tt], s[tt] - v2);
        __threadfence();
        __syncthreads();
        if (tt == 0) atomicExch(&done[1], 1);
    }
    if (threadIdx.x == 0) {
        while (atomicAdd(&done[1], 0) == 0) __builtin_amdgcn_s_sleep(1);
    }
    __syncthreads();
    __threadfence();
    int base = atomicAdd(&bs[lb], 0);
    s[threadIdx.x] = v;
    __syncthreads();
    for (int off = 1; off < 256; off <<= 1) {
        int u = (threadIdx.x >= off) ? s[threadIdx.x - off] : 0;
        __syncthreads();
        s[threadIdx.x] += u;
        __syncthreads();
    }
    int incl = s[threadIdx.x];
    if (t < n) rp[t] = base + incl - v;
    if (t == n - 1) rp[n] = base + incl;
}

// ---------------------------------------------------------------------------
// fill_both: atomic-free scatter using precomputed ranks (max TLP)
// ---------------------------------------------------------------------------
__global__ __launch_bounds__(256) void fill_both(
    const int* __restrict__ d1, const int* __restrict__ s1,
    const int* __restrict__ et1, const int* __restrict__ ets1,
    const int* __restrict__ rp1, const int* __restrict__ rk1, uint2* __restrict__ ed1,
    const int* __restrict__ d2, const int* __restrict__ s2,
    const int* __restrict__ et2, const int* __restrict__ ets2,
    const int* __restrict__ rp2, const int* __restrict__ rk2, uint2* __restrict__ ed2) {
    int t = blockIdx.x * 256 + threadIdx.x;
    if (t < E1C) {
        int pos = rp1[d1[t]] + rk1[t];
        ed1[pos] = make_uint2((unsigned)s1[t],
                              (unsigned)(et1[t] | (ets1[t] << 16)));
    } else {
        t -= E1C;
        if (t < E2C) {
            int pos = rp2[d2[t]] + rk2[t];
            ed2[pos] = make_uint2((unsigned)s2[t],
                                  (unsigned)(et2[t] | (ets2[t] << 16)));
        }
    }
}

// ---------------------------------------------------------------------------
// Fused aggregation — depth-3 rotation pipeline (was depth-2): 3 live sets +
// one loading, so KV/TA/TB loads are issued 3 iterations before use. Same
// 32-lane/2-slot layout and numerics as the measured-best depth-2 version;
// only the prefetch distance changes.
// ---------------------------------------------------------------------------
#define LOADSET(SET, DSC) { \
    int t_ = (int)(DSC.y & 0xFFFF), ts_ = (int)(DSC.y >> 16); \
    ta##SET = *(const float4*)(TA + t_ * 128 + co); \
    tb##SET = *(const float4*)(TB + ts_ * 128 + co); \
    const unsigned short* kv_ = KV + (size_t)DSC.x * 256; \
    ku##SET = *(const ushort4*)(kv_ + co); \
    vu##SET = *(const ushort4*)(kv_ + 128 + co); }

#define COMPUTE(SET) { \
    float e0c = ta##SET.x + tb##SET.x, e1c = ta##SET.y + tb##SET.y; \
    float e2c = ta##SET.z + tb##SET.z, e3c = ta##SET.w + tb##SET.w; \
    float pp = q4.x * (b2f(ku##SET.x) + e0c) + q4.y * (b2f(ku##SET.y) + e1c) \
             + q4.z * (b2f(ku##SET.z) + e2c) + q4.w * (b2f(ku##SET.w) + e3c); \
    pp = red16(pp); \
    float a = __expf(pp * 0.125f); \
    ax += a * (b2f(vu##SET.x) + e0c); ay += a * (b2f(vu##SET.y) + e1c); \
    az += a * (b2f(vu##SET.z) + e2c); aw += a * (b2f(vu##SET.w) + e3c); \
    suma += a; }

static __device__ __forceinline__ void edge_accum(
    int beg, int end, int s, int co, float4 q4,
    const uint2* __restrict__ ED, const float* __restrict__ TA,
    const float* __restrict__ TB, const unsigned short* __restrict__ KV,
    float& ax, float& ay, float& az, float& aw, float& suma) {
    int p = beg + s;
    if (p >= end) return;

    uint2 d0 = ED[p];
    int pA = p + 2; bool mA = pA < end;
    uint2 d1 = ED[mA ? pA : beg];
    int pB = p + 4; bool mB = pB < end;
    uint2 d2 = ED[mB ? pB : beg];
    int pT = p + 6; bool mC = pT < end;
    uint2 dL = ED[mC ? pT : beg];       // descriptor of the set to load next

    float4 ta0, tb0, ta1, tb1, ta2, tb2, ta3, tb3;
    ushort4 ku0, vu0, ku1, vu1, ku2, vu2, ku3, vu3;

    LOADSET(0, d0)
    LOADSET(1, d1)
    LOADSET(2, d2)
    for (;;) {
        int pE = pT + 2; bool mE = pE < end;
        uint2 dN = ED[mE ? pE : beg];
        LOADSET(3, dL)
        COMPUTE(0)
        if (!mA) break;
        ta0 = ta1; tb0 = tb1; ku0 = ku1; vu0 = vu1;
        ta1 = ta2; tb1 = tb2; ku1 = ku2; vu1 = vu2;
        ta2 = ta3; tb2 = tb3; ku2 = ku3; vu2 = vu3;
        dL = dN;
        mA = mB; mB = mC; mC = mE; pT = pE;
    }
}

#undef LOADSET
#undef COMPUTE

__global__ __launch_bounds__(256) void agg_layer1(
    const int* __restrict__ rowptr, const uint2* __restrict__ ED,
    const float* __restrict__ TA, const float* __restrict__ TB,
    const float* __restrict__ QR, const unsigned short* __restrict__ KV,
    const float* __restrict__ Wbeta,
    const float* __restrict__ ln_g, const float* __restrict__ ln_b,
    unsigned short* __restrict__ hout, int n) {
    int wid = (blockIdx.x * blockDim.x + threadIdx.x) >> 6;
    int lane = threadIdx.x & 63;
    if (wid >= n) return;
    int s = lane >> 5, cg = lane & 15;
    int co = ((lane >> 4) & 1) * 64 + 4 * cg;
    int beg = rowptr[wid], end = rowptr[wid + 1];
    float4 q4 = *(const float4*)(QR + (size_t)wid * 256 + co);
    float ax = 0.f, ay = 0.f, az = 0.f, aw = 0.f, suma = 0.f;
    edge_accum(beg, end, s, co, q4, ED, TA, TB, KV, ax, ay, az, aw, suma);
    ax += __shfl_xor(ax, 32); ay += __shfl_xor(ay, 32);
    az += __shfl_xor(az, 32); aw += __shfl_xor(aw, 32);
    suma += __shfl_xor(suma, 32);
    float inv_s = 1.f / (suma + 1e-16f);
    float ox = ax * inv_s, oy = ay * inv_s, oz = az * inv_s, ow = aw * inv_s;
    float4 r4 = *(const float4*)(QR + (size_t)wid * 256 + 128 + co);
    float4 wo = *(const float4*)(Wbeta + co);
    float4 wr = *(const float4*)(Wbeta + 128 + co);
    float4 wd = *(const float4*)(Wbeta + 256 + co);
    float pb = wo.x * ox + wr.x * r4.x + wd.x * (ox - r4.x)
             + wo.y * oy + wr.y * r4.y + wd.y * (oy - r4.y)
             + wo.z * oz + wr.z * r4.z + wd.z * (oz - r4.z)
             + wo.w * ow + wr.w * r4.w + wd.w * (ow - r4.w);
    pb = red16(pb);
    pb += __shfl_xor(pb, 16);
    float beta = 1.f / (1.f + __expf(-pb));
    float gx = beta * r4.x + (1.f - beta) * ox;
    float gy = beta * r4.y + (1.f - beta) * oy;
    float gz = beta * r4.z + (1.f - beta) * oz;
    float gw = beta * r4.w + (1.f - beta) * ow;
    float sm = gx + gy + gz + gw;
    float sq = gx * gx + gy * gy + gz * gz + gw * gw;
    sm = red16(sm); sm += __shfl_xor(sm, 16);
    sq = red16(sq); sq += __shfl_xor(sq, 16);
    float mu = sm * (1.f / 128.f);
    float var = sq * (1.f / 128.f) - mu * mu;
    float inv = rsqrtf(var + 1e-5f);
    float4 lg = *(const float4*)(ln_g + co);
    float4 lb = *(const float4*)(ln_b + co);
    float yx = (gx - mu) * inv * lg.x + lb.x;
    float yy = (gy - mu) * inv * lg.y + lb.y;
    float yz = (gz - mu) * inv * lg.z + lb.z;
    float yw = (gw - mu) * inv * lg.w + lb.w;
    const float ISQ2 = 0.70710678118654752f;
    yx = 0.5f * yx * (1.f + erff(yx * ISQ2));
    yy = 0.5f * yy * (1.f + erff(yy * ISQ2));
    yz = 0.5f * yz * (1.f + erff(yz * ISQ2));
    yw = 0.5f * yw * (1.f + erff(yw * ISQ2));
    if (s == 0) {
        ushort4 hv;
        hv.x = f2b(yx); hv.y = f2b(yy); hv.z = f2b(yz); hv.w = f2b(yw);
        *(ushort4*)(hout + (size_t)wid * 128 + co) = hv;
    }
}

__global__ __launch_bounds__(256) void agg_layer2(
    const int* __restrict__ rowptr, const uint2* __restrict__ ED,
    const float* __restrict__ TA, const float* __restrict__ TB,
    const float* __restrict__ QR, const unsigned short* __restrict__ KV,
    const float* __restrict__ Wbeta,
    float* __restrict__ o, int n) {
    int wid = (blockIdx.x * blockDim.x + threadIdx.x) >> 6;
    int lane = threadIdx.x & 63;
    if (wid >= n) return;
    int s = lane >> 5, cg = lane & 15;
    int co = ((lane >> 4) & 1) * 64 + 4 * cg;
    int beg = rowptr[wid], end = rowptr[wid + 1];
    float4 q4 = *(const float4*)(QR + (size_t)wid * 192 + co);
    float ax = 0.f, ay = 0.f, az = 0.f, aw = 0.f, suma = 0.f;
    edge_accum(beg, end, s, co, q4, ED, TA, TB, KV, ax, ay, az, aw, suma);
    ax += __shfl_xor(ax, 32); ay += __shfl_xor(ay, 32);
    az += __shfl_xor(az, 32); aw += __shfl_xor(aw, 32);
    suma += __shfl_xor(suma, 32);
    float inv_s = 1.f / (suma + 1e-16f);
    float ox = ax * inv_s, oy = ay * inv_s, oz = az * inv_s, ow = aw * inv_s;
    ox = 0.5f * (ox + __shfl_xor(ox, 16));
    oy = 0.5f * (oy + __shfl_xor(oy, 16));
    oz = 0.5f * (oz + __shfl_xor(oz, 16));
    ow = 0.5f * (ow + __shfl_xor(ow, 16));
    float4 r4 = *(const float4*)(QR + (size_t)wid * 192 + 128 + 4 * cg);
    float4 wo = *(const float4*)(Wbeta + 4 * cg);
    float4 wr = *(const float4*)(Wbeta + 64 + 4 * cg);
    float4 wd = *(const float4*)(Wbeta + 128 + 4 * cg);
    float pb = wo.x * ox + wr.x * r4.x + wd.x * (ox - r4.x)
             + wo.y * oy + wr.y * r4.y + wd.y * (oy - r4.y)
             + wo.z * oz + wr.z * r4.z + wd.z * (oz - r4.z)
             + wo.w * ow + wr.w * r4.w + wd.w * (ow - r4.w);
    pb = red16(pb);
    float beta = 1.f / (1.f + __expf(-pb));
    float vx = beta * r4.x + (1.f - beta) * ox;
    float vy = beta * r4.y + (1.f - beta) * oy;
    float vz = beta * r4.z + (1.f - beta) * oz;
    float vw = beta * r4.w + (1.f - beta) * ow;
    float m = fmaxf(fmaxf(vx, vy), fmaxf(vz, vw));
    m = red16max(m);
    float se = __expf(vx - m) + __expf(vy - m) + __expf(vz - m) + __expf(vw - m);
    se = red16(se);
    float lse = m + logf(se);
    if (lane < 16)
        *(float4*)(o + (size_t)wid * 64 + 4 * cg) =
            make_float4(vx - lse, vy - lse, vz - lse, vw - lse);
}

extern "C" void kernel_launch(void* const* d_in, const int* in_sizes, int n_in,
                              void* d_out, int out_size, void* d_ws, size_t ws_size,
                              hipStream_t stream) {
    const float* x        = (const float*)d_in[0];
    const int*   ei1_src  = (const int*)d_in[1];
    const int*   ei1_dst  = (const int*)d_in[2];
    const int*   et1      = (const int*)d_in[3];
    const int*   ets1     = (const int*)d_in[4];
    const int*   ei2_src  = (const int*)d_in[5];
    const int*   ei2_dst  = (const int*)d_in[6];
    const int*   et2      = (const int*)d_in[7];
    const int*   ets2     = (const int*)d_in[8];
    const float* edge_W   = (const float*)d_in[9];
    const float* edge_b   = (const float*)d_in[10];
    const float* time_W   = (const float*)d_in[11];
    const float* time_b   = (const float*)d_in[12];
    const float* Wq1      = (const float*)d_in[13];
    const float* bq1      = (const float*)d_in[14];
    const float* Wk1      = (const float*)d_in[15];
    const float* bk1      = (const float*)d_in[16];
    const float* Wv1      = (const float*)d_in[17];
    const float* bv1      = (const float*)d_in[18];
    const float* We1      = (const float*)d_in[19];
    const float* Wskip1   = (const float*)d_in[20];
    const float* bskip1   = (const float*)d_in[21];
    const float* Wbeta1   = (const float*)d_in[22];
    const float* ln_g     = (const float*)d_in[23];
    const float* ln_b     = (const float*)d_in[24];
    const float* Wq2      = (const float*)d_in[25];
    const float* bq2      = (const float*)d_in[26];
    const float* Wk2      = (const float*)d_in[27];
    const float* bk2      = (const float*)d_in[28];
    const float* Wv2      = (const float*)d_in[29];
    const float* bv2      = (const float*)d_in[30];
    const float* We2      = (const float*)d_in[31];
    const float* Wskip2   = (const float*)d_in[32];
    const float* bskip2   = (const float*)d_in[33];
    const float* Wbeta2   = (const float*)d_in[34];

    float* ws = (float*)d_ws;
    unsigned short* xb  = (unsigned short*)(ws + OFF_XB);
    float* qr1          = ws + OFF_QR1;
    unsigned short* kv1 = (unsigned short*)(ws + OFF_KV1);
    unsigned short* h   = (unsigned short*)(ws + OFF_H);
    float* qr2          = ws + OFF_QR2;
    unsigned short* kv2 = (unsigned short*)(ws + OFF_KV2);
    unsigned short* wb1 = (unsigned short*)(ws + OFF_WB1);
    float* bp1          = ws + OFF_BP1;
    unsigned short* wb2 = (unsigned short*)(ws + OFF_WB2);
    float* bp2          = ws + OFF_BP2;
    float* ta1          = ws + OFF_TA1;
    float* tb1          = ws + OFF_TB1;
    float* ta2          = ws + OFF_TA2;
    float* tb2          = ws + OFF_TB2;
    int*   rp1          = (int*)(ws + OFF_RP1);
    int*   cur1         = (int*)(ws + OFF_CUR1);
    uint2* ed1          = (uint2*)(ws + OFF_ED1);
    int*   bs1          = (int*)(ws + OFF_BS1);
    int*   rp2          = (int*)(ws + OFF_RP2);
    int*   cur2         = (int*)(ws + OFF_CUR2);
    uint2* ed2          = (uint2*)(ws + OFF_ED2);
    int*   bs2          = (int*)(ws + OFF_BS2);
    int*   done         = (int*)(ws + OFF_DONE);
    int*   rk1          = (int*)(ws + OFF_RK1);
    int*   rk2          = (int*)(ws + OFF_RK2);

    prep<<<2048, 256, 0, stream>>>(
        x, xb,
        Wk1, Wv1, Wq1, Wskip1, bk1, bv1, bq1, bskip1,
        Wk2, Wv2, Wq2, Wskip2, bk2, bv2, bq2, bskip2,
        wb1, bp1, wb2, bp2,
        edge_W, edge_b, time_W, time_b, We1, We2,
        ta1, tb1, ta2, tb2, cur1, cur2, done);
    mega_l1<<<KV1B + QR1B + CNTB, 256, 0, stream>>>(
        xb, wb1, bp1, kv1, qr1, ei1_dst, ei2_dst, cur1, cur2, rk1, rk2);
    csr_scan<<<NB1 + NB2, 256, 0, stream>>>(cur1, bs1, rp1, cur2, bs2, rp2, done);
    fill_both<<<FILLB, 256, 0, stream>>>(
        ei1_dst, ei1_src, et1, ets1, rp1, rk1, ed1,
        ei2_dst, ei2_src, et2, ets2, rp2, rk2, ed2);
    agg_layer1<<<(N1 + 3) / 4, 256, 0, stream>>>(rp1, ed1,
        ta1, tb1, qr1, kv1, Wbeta1, ln_g, ln_b, h, N1);
    gemm_l2<<<KV2B + QR2B, 256, 0, stream>>>(h, wb2, bp2, kv2, qr2);
    agg_layer2<<<(N2 + 3) / 4, 256, 0, stream>>>(rp2, ed2,
        ta2, tb2, qr2, kv2, Wbeta2, (float*)d_out, N2);
}